// Round 13
// baseline (505.043 us; speedup 1.0000x reference)
//
#include <hip/hip_runtime.h>
#include <hip/hip_bf16.h>
#include <cstddef>

#define HW 4096   // 64*64

// ---------------------------------------------------------------------------
// Tiled projection + fused per-head l2norm (probe2-verified design).
// grid (64 pixel-tiles, 6 images), block 256 (thread = out channel).
// ---------------------------------------------------------------------------
__global__ __launch_bounds__(256) void proj_kernel(
    const float* __restrict__ x, const float* __restrict__ Wq, const float* __restrict__ bq,
    const float* __restrict__ Ws, const float* __restrict__ bs, const float* __restrict__ scale,
    float* __restrict__ q_n, float* __restrict__ s_n) {
  const int n = blockIdx.y;
  const int p0 = blockIdx.x * 64;
  const int t = threadIdx.x;
  const float* __restrict__ W = (n == 0) ? Wq : Ws;
  const float* __restrict__ B = (n == 0) ? bq : bs;

  __shared__ float Wl[256][17];
  __shared__ float Xl[16][64];

  float4 acc[16];
#pragma unroll
  for (int i = 0; i < 16; ++i) acc[i] = make_float4(0.f, 0.f, 0.f, 0.f);

  for (int cc = 0; cc < 256; cc += 16) {
    __syncthreads();
#pragma unroll
    for (int i = 0; i < 16; ++i) {
      int co = i * 16 + (t >> 4), ci = t & 15;
      Wl[co][ci] = W[(size_t)co * 256 + cc + ci];
    }
#pragma unroll
    for (int i = 0; i < 4; ++i) {
      int ci = i * 4 + (t >> 6), p = t & 63;
      Xl[ci][p] = x[(size_t)n * 256 * HW + (size_t)(cc + ci) * HW + p0 + p];
    }
    __syncthreads();
    for (int ci = 0; ci < 16; ++ci) {
      float w = Wl[t][ci];
#pragma unroll
      for (int i = 0; i < 16; ++i) {
        float4 xv = *(const float4*)&Xl[ci][i * 4];
        acc[i].x += w * xv.x; acc[i].y += w * xv.y;
        acc[i].z += w * xv.z; acc[i].w += w * xv.w;
      }
    }
  }

  const float bias = B[t];
  const float qs = scale[0] * 0.17677669529663687f;   // scale * HD^-0.5
  float* __restrict__ outp = (n == 0) ? q_n : (s_n + (size_t)(n - 1) * HW * 256);
#pragma unroll
  for (int i = 0; i < 16; ++i) {
    float vv[4] = {acc[i].x, acc[i].y, acc[i].z, acc[i].w};
#pragma unroll
    for (int u = 0; u < 4; ++u) {
      float v = vv[u] + bias;
      float ss = v * v;
      ss += __shfl_xor(ss, 1);
      ss += __shfl_xor(ss, 2);
      ss += __shfl_xor(ss, 4);
      ss += __shfl_xor(ss, 8);
      ss += __shfl_xor(ss, 16);          // 32-lane head group
      v /= fmaxf(sqrtf(ss), 1e-12f);
      if (n == 0) v *= qs;
      outp[(size_t)(p0 + i * 4 + u) * 256 + t] = v;
    }
  }
}

// ---------------------------------------------------------------------------
// Patch aggregation -> c_s[8][2560][32], mask[2560] (probe2-verified).
// ---------------------------------------------------------------------------
__global__ __launch_bounds__(256) void agg_kernel(
    const float* __restrict__ delta, const float* __restrict__ s_n,
    float* __restrict__ c_s, float* __restrict__ mask) {
  const int s = blockIdx.x;
  const int k = blockIdx.y;
  const int t = threadIdx.x;
  __shared__ float fgl[16];
  const int sy = (s >> 4) * 4, sx = (s & 15) * 4;
  if (t < 16) {
    int y0 = (sy + (t >> 2)) * 8, x0 = (sx + (t & 3)) * 8;
    fgl[t] = delta[(size_t)k * 512 * 512 + (size_t)y0 * 512 + x0];
  }
  __syncthreads();
  const int h = t >> 5, d = t & 31;
  float af = 0.f, ab = 0.f;
#pragma unroll
  for (int l = 0; l < 16; ++l) {
    int pix = (sy + (l >> 2)) * 64 + sx + (l & 3);
    float sv = s_n[((size_t)k * HW + pix) * 256 + h * 32 + d];
    float f = fgl[l];
    af += f * sv;
    ab += (1.f - f) * sv;
  }
  float ssf = af * af, ssb = ab * ab;
#pragma unroll
  for (int m = 1; m <= 16; m <<= 1) {
    ssf += __shfl_xor(ssf, m);
    ssb += __shfl_xor(ssb, m);
  }
  float vf = af / fmaxf(sqrtf(ssf), 1e-12f);
  float vb = ab / fmaxf(sqrtf(ssb), 1e-12f);
  const int jf = k * 512 + s, jb = jf + 256;
  c_s[((size_t)h * 2560 + jf) * 32 + d] = vf;
  c_s[((size_t)h * 2560 + jb) * 32 + d] = vb;
  if (t == 0) {
    float fs = 0.f;
#pragma unroll
    for (int l = 0; l < 16; ++l) fs += fgl[l];
    mask[jf] = (fs < 1.f) ? -1e30f : 0.f;
    mask[jb] = ((16.f - fs) < 1.f) ? -1e30f : 0.f;
  }
}

// ---------------------------------------------------------------------------
// Attention partials, 2 pixels/thread register blocking.
// grid (8 pixel-tiles of 512, 8 heads, 10 key-tiles), block 256.
// Per jj: 8 ds_read_b128 amortized over 64 FMAs -> VALU-bound, FMA-rich.
// ---------------------------------------------------------------------------
__global__ __launch_bounds__(256) void attn_kernel(
    const float* __restrict__ q_n, const float* __restrict__ c_s,
    const float* __restrict__ mask, float* __restrict__ part) {
  const int t = threadIdx.x;
  const int pb = blockIdx.x * 512;
  const int h = blockIdx.y;
  const int z = blockIdx.z;          // key tile
  __shared__ float csl[256 * 32];
  __shared__ float ml[256];
  const int j0 = z * 256;

#pragma unroll
  for (int i = 0; i < 8; ++i) {
    int idx = i * 256 + t;           // 2048 float4s = 256 keys * 8
    int key = idx >> 3, d4 = idx & 7;
    *(float4*)&csl[idx * 4] =
        *(const float4*)&c_s[((size_t)h * 2560 + j0 + key) * 32 + d4 * 4];
  }
  ml[t] = mask[j0 + t];

  const int p0 = pb + t;
  const int p1 = pb + 256 + t;
  float4 qa[8], qb[8];
#pragma unroll
  for (int i = 0; i < 8; ++i) {
    qa[i] = *(const float4*)&q_n[(size_t)p0 * 256 + h * 32 + i * 4];
    qb[i] = *(const float4*)&q_n[(size_t)p1 * 256 + h * 32 + i * 4];
  }
  __syncthreads();

  const float cv = ((j0 & 511) < 256) ? 1.f : 0.f;  // whole 256-tile fg or bg
  float num0 = 0.f, den0 = 0.f, num1 = 0.f, den1 = 0.f;
  for (int jj = 0; jj < 256; ++jj) {
    float d0 = 0.f, d1 = 0.f;
#pragma unroll
    for (int i = 0; i < 8; ++i) {
      float4 c4 = *(const float4*)&csl[jj * 32 + i * 4];
      d0 += qa[i].x * c4.x + qa[i].y * c4.y + qa[i].z * c4.z + qa[i].w * c4.w;
      d1 += qb[i].x * c4.x + qb[i].y * c4.y + qb[i].z * c4.z + qb[i].w * c4.w;
    }
    float m = ml[jj];
    float e0 = __expf(d0 + m);       // masked -> 0
    float e1 = __expf(d1 + m);
    den0 += e0; den1 += e1;
    num0 += cv * e0; num1 += cv * e1;
  }
  float* o0 = &part[(((size_t)z * 8 + h) * HW + p0) * 2];
  o0[0] = num0; o0[1] = den0;
  float* o1 = &part[(((size_t)z * 8 + h) * HW + p1) * 2];
  o1[0] = num1; o1[1] = den1;
}

// merge 10 key-tile partials: xo[h*HW+p]
__global__ __launch_bounds__(256) void merge_kernel(const float* __restrict__ part,
                                                    float* __restrict__ xo) {
  int idx = blockIdx.x * 256 + threadIdx.x;   // 32768 = h*HW+p
  int h = idx >> 12, p = idx & 4095;
  float n = 0.f, d = 0.f;
#pragma unroll
  for (int z = 0; z < 10; ++z) {
    const float* o = &part[(((size_t)z * 8 + h) * HW + p) * 2];
    n += o[0];
    d += o[1];
  }
  xo[idx] = n / d;
}

// ---------------------------------------------------------------------------
// Conv (cross-correlation) — naive
// ---------------------------------------------------------------------------
template <int CI, int KS, int PAD>
__global__ __launch_bounds__(256) void n_conv(
    const float* __restrict__ in, const float* __restrict__ w,
    const float* __restrict__ b, float* __restrict__ out) {
  const int co = blockIdx.y;
  const int p = blockIdx.x * 256 + threadIdx.x;
  const int y = p >> 6, xx = p & 63;
  float acc = b[co];
  for (int ci = 0; ci < CI; ++ci)
#pragma unroll
    for (int ky = 0; ky < KS; ++ky) {
      int iy = y + ky - PAD;
      if (iy < 0 || iy >= 64) continue;
#pragma unroll
      for (int kx = 0; kx < KS; ++kx) {
        int ix = xx + kx - PAD;
        if (ix < 0 || ix >= 64) continue;
        acc += in[(size_t)ci * HW + iy * 64 + ix] *
               w[(size_t)((co * CI + ci) * KS + ky) * KS + kx];
      }
    }
  out[(size_t)co * HW + p] = acc;
}

// ---------------------------------------------------------------------------
// GroupNorm stats, two-stage.
// ---------------------------------------------------------------------------
__global__ __launch_bounds__(256) void gnstatsA(const float* __restrict__ in,
                                                float* __restrict__ stp, int cpg) {
  __shared__ float sh[256], sh2[256];
  const int g = blockIdx.x, b = blockIdx.y, t = threadIdx.x;
  const int n = cpg * HW;
  const int chunk = n >> 4;
  const float* __restrict__ base = in + (size_t)g * n + (size_t)b * chunk;
  float s = 0.f, ss = 0.f;
  for (int i = t; i < chunk; i += 256) {
    float v = base[i];
    s += v;
    ss += v * v;
  }
  sh[t] = s; sh2[t] = ss;
  __syncthreads();
  for (int w = 128; w > 0; w >>= 1) {
    if (t < w) { sh[t] += sh[t + w]; sh2[t] += sh2[t + w]; }
    __syncthreads();
  }
  if (t == 0) { stp[(g * 16 + b) * 2] = sh[0]; stp[(g * 16 + b) * 2 + 1] = sh2[0]; }
}

__global__ __launch_bounds__(64) void gnstatsB(const float* __restrict__ stp,
                                               float* __restrict__ st, int cpg) {
  const int g = blockIdx.x;
  if (threadIdx.x == 0) {
    float S = 0.f, SS = 0.f;
    for (int b = 0; b < 16; ++b) { S += stp[(g * 16 + b) * 2]; SS += stp[(g * 16 + b) * 2 + 1]; }
    float n = (float)(cpg * HW);
    float mean = S / n;
    float var = SS / n - mean * mean;
    st[g * 2] = mean;
    st[g * 2 + 1] = 1.0f / sqrtf(var + 1e-5f);
  }
}

// GroupNorm apply + ReLU, float32 out (reference output dtype).
__global__ __launch_bounds__(256) void gn_apply(
    const float* __restrict__ in, float* __restrict__ out, const float* __restrict__ st,
    const float* __restrict__ gs, const float* __restrict__ gb, int cpg) {
  const int idx = blockIdx.x * 256 + threadIdx.x;
  const int c = idx >> 12;
  const int g = c / cpg;
  float v = (in[idx] - st[g * 2]) * st[g * 2 + 1] * gs[c] + gb[c];
  out[idx] = fmaxf(v, 0.f);
}

// ---------------------------------------------------------------------------
extern "C" void kernel_launch(void* const* d_in, const int* in_sizes, int n_in,
                              void* d_out, int out_size, void* d_ws, size_t ws_size,
                              hipStream_t stream) {
  const float* x     = (const float*)d_in[0];
  const float* delta = (const float*)d_in[1];
  const float* Wq    = (const float*)d_in[2];
  const float* bq    = (const float*)d_in[3];
  const float* Ws    = (const float*)d_in[4];
  const float* bs    = (const float*)d_in[5];
  const float* scale = (const float*)d_in[6];
  const float* c1w = (const float*)d_in[7],  *c1b = (const float*)d_in[8];
  const float* g1s = (const float*)d_in[9],  *g1b = (const float*)d_in[10];
  const float* c2w = (const float*)d_in[11], *c2b = (const float*)d_in[12];
  const float* g2s = (const float*)d_in[13], *g2b = (const float*)d_in[14];
  const float* c3w = (const float*)d_in[15], *c3b = (const float*)d_in[16];
  const float* g3s = (const float*)d_in[17], *g3b = (const float*)d_in[18];

  float* ws   = (float*)d_ws;
  float* q_n  = ws;                       // 1,048,576
  float* s_n  = q_n + 1048576;            // 5,242,880
  float* c_s  = s_n + 5242880;            //   655,360
  float* mask = c_s + 655360;             //     2,560
  float* xo   = mask + 2560;              //    32,768
  float* st   = xo + 32768;               //        32
  float* stp  = st + 32;                  //       512 (128 used)
  float* un   = stp + 512;                // union: part then conv temps
  float* part = un;                       //   655,360 (10*8*4096*2)
  float* t1   = un;                       //    65,536
  float* a1   = un + 65536;               //    65,536
  float* t2   = un + 131072;              //   262,144
  float* a2   = un + 393216;              //   262,144
  float* t3   = un + 655360;              //   524,288

  proj_kernel<<<dim3(64, 6), 256, 0, stream>>>(x, Wq, bq, Ws, bs, scale, q_n, s_n);
  agg_kernel<<<dim3(256, 5), 256, 0, stream>>>(delta, s_n, c_s, mask);
  attn_kernel<<<dim3(8, 8, 10), 256, 0, stream>>>(q_n, c_s, mask, part);
  merge_kernel<<<128, 256, 0, stream>>>(part, xo);

  n_conv<8, 5, 2><<<dim3(16, 16), 256, 0, stream>>>(xo, c1w, c1b, t1);
  gnstatsA<<<dim3(4, 16), 256, 0, stream>>>(t1, stp, 4);
  gnstatsB<<<4, 64, 0, stream>>>(stp, st, 4);
  gn_apply<<<256, 256, 0, stream>>>(t1, a1, st, g1s, g1b, 4);

  n_conv<16, 3, 1><<<dim3(16, 64), 256, 0, stream>>>(a1, c2w, c2b, t2);
  gnstatsA<<<dim3(4, 16), 256, 0, stream>>>(t2, stp + 128, 16);
  gnstatsB<<<4, 64, 0, stream>>>(stp + 128, st + 8, 16);
  gn_apply<<<1024, 256, 0, stream>>>(t2, a2, st + 8, g2s, g2b, 16);

  n_conv<64, 3, 1><<<dim3(16, 128), 256, 0, stream>>>(a2, c3w, c3b, t3);
  gnstatsA<<<dim3(4, 16), 256, 0, stream>>>(t3, stp + 256, 32);
  gnstatsB<<<4, 64, 0, stream>>>(stp + 256, st + 16, 32);
  gn_apply<<<2048, 256, 0, stream>>>(t3, (float*)d_out, st + 16, g3s, g3b, 32);
}

// Round 14
// 466.880 us; speedup vs baseline: 1.0817x; 1.0817x over previous
//
#include <hip/hip_runtime.h>
#include <hip/hip_bf16.h>
#include <cstddef>

#define HW 4096   // 64*64

// ---------------------------------------------------------------------------
// Tiled projection + fused per-head l2norm (probe2-verified design).
// grid (64 pixel-tiles, 6 images), block 256 (thread = out channel).
// ---------------------------------------------------------------------------
__global__ __launch_bounds__(256) void proj_kernel(
    const float* __restrict__ x, const float* __restrict__ Wq, const float* __restrict__ bq,
    const float* __restrict__ Ws, const float* __restrict__ bs, const float* __restrict__ scale,
    float* __restrict__ q_n, float* __restrict__ s_n) {
  const int n = blockIdx.y;
  const int p0 = blockIdx.x * 64;
  const int t = threadIdx.x;
  const float* __restrict__ W = (n == 0) ? Wq : Ws;
  const float* __restrict__ B = (n == 0) ? bq : bs;

  __shared__ float Wl[256][17];
  __shared__ float Xl[16][64];

  float4 acc[16];
#pragma unroll
  for (int i = 0; i < 16; ++i) acc[i] = make_float4(0.f, 0.f, 0.f, 0.f);

  for (int cc = 0; cc < 256; cc += 16) {
    __syncthreads();
#pragma unroll
    for (int i = 0; i < 16; ++i) {
      int co = i * 16 + (t >> 4), ci = t & 15;
      Wl[co][ci] = W[(size_t)co * 256 + cc + ci];
    }
#pragma unroll
    for (int i = 0; i < 4; ++i) {
      int ci = i * 4 + (t >> 6), p = t & 63;
      Xl[ci][p] = x[(size_t)n * 256 * HW + (size_t)(cc + ci) * HW + p0 + p];
    }
    __syncthreads();
    for (int ci = 0; ci < 16; ++ci) {
      float w = Wl[t][ci];
#pragma unroll
      for (int i = 0; i < 16; ++i) {
        float4 xv = *(const float4*)&Xl[ci][i * 4];
        acc[i].x += w * xv.x; acc[i].y += w * xv.y;
        acc[i].z += w * xv.z; acc[i].w += w * xv.w;
      }
    }
  }

  const float bias = B[t];
  const float qs = scale[0] * 0.17677669529663687f;   // scale * HD^-0.5
  float* __restrict__ outp = (n == 0) ? q_n : (s_n + (size_t)(n - 1) * HW * 256);
#pragma unroll
  for (int i = 0; i < 16; ++i) {
    float vv[4] = {acc[i].x, acc[i].y, acc[i].z, acc[i].w};
#pragma unroll
    for (int u = 0; u < 4; ++u) {
      float v = vv[u] + bias;
      float ss = v * v;
      ss += __shfl_xor(ss, 1);
      ss += __shfl_xor(ss, 2);
      ss += __shfl_xor(ss, 4);
      ss += __shfl_xor(ss, 8);
      ss += __shfl_xor(ss, 16);          // 32-lane head group
      v /= fmaxf(sqrtf(ss), 1e-12f);
      if (n == 0) v *= qs;
      outp[(size_t)(p0 + i * 4 + u) * 256 + t] = v;
    }
  }
}

// ---------------------------------------------------------------------------
// Patch aggregation -> c_s[8][2560][32], mask[2560] (probe2-verified).
// ---------------------------------------------------------------------------
__global__ __launch_bounds__(256) void agg_kernel(
    const float* __restrict__ delta, const float* __restrict__ s_n,
    float* __restrict__ c_s, float* __restrict__ mask) {
  const int s = blockIdx.x;
  const int k = blockIdx.y;
  const int t = threadIdx.x;
  __shared__ float fgl[16];
  const int sy = (s >> 4) * 4, sx = (s & 15) * 4;
  if (t < 16) {
    int y0 = (sy + (t >> 2)) * 8, x0 = (sx + (t & 3)) * 8;
    fgl[t] = delta[(size_t)k * 512 * 512 + (size_t)y0 * 512 + x0];
  }
  __syncthreads();
  const int h = t >> 5, d = t & 31;
  float af = 0.f, ab = 0.f;
#pragma unroll
  for (int l = 0; l < 16; ++l) {
    int pix = (sy + (l >> 2)) * 64 + sx + (l & 3);
    float sv = s_n[((size_t)k * HW + pix) * 256 + h * 32 + d];
    float f = fgl[l];
    af += f * sv;
    ab += (1.f - f) * sv;
  }
  float ssf = af * af, ssb = ab * ab;
#pragma unroll
  for (int m = 1; m <= 16; m <<= 1) {
    ssf += __shfl_xor(ssf, m);
    ssb += __shfl_xor(ssb, m);
  }
  float vf = af / fmaxf(sqrtf(ssf), 1e-12f);
  float vb = ab / fmaxf(sqrtf(ssb), 1e-12f);
  const int jf = k * 512 + s, jb = jf + 256;
  c_s[((size_t)h * 2560 + jf) * 32 + d] = vf;
  c_s[((size_t)h * 2560 + jb) * 32 + d] = vb;
  if (t == 0) {
    float fs = 0.f;
#pragma unroll
    for (int l = 0; l < 16; ++l) fs += fgl[l];
    mask[jf] = (fs < 1.f) ? -1e30f : 0.f;
    mask[jb] = ((16.f - fs) < 1.f) ? -1e30f : 0.f;
  }
}

// ---------------------------------------------------------------------------
// Attention partials: 2 px/thread, 128-key tiles.
// grid (8 pixel-tiles of 512, 8 heads, 20 key-tiles), block 256. LDS ~17KB.
// ---------------------------------------------------------------------------
__global__ __launch_bounds__(256) void attn_kernel(
    const float* __restrict__ q_n, const float* __restrict__ c_s,
    const float* __restrict__ mask, float* __restrict__ part) {
  const int t = threadIdx.x;
  const int pb = blockIdx.x * 512;
  const int h = blockIdx.y;
  const int z = blockIdx.z;          // key tile (128 keys)
  __shared__ float csl[128 * 32];
  __shared__ float ml[128];
  const int j0 = z * 128;

#pragma unroll
  for (int i = 0; i < 4; ++i) {
    int idx = i * 256 + t;           // 1024 float4s = 128 keys * 8
    int key = idx >> 3, d4 = idx & 7;
    *(float4*)&csl[idx * 4] =
        *(const float4*)&c_s[((size_t)h * 2560 + j0 + key) * 32 + d4 * 4];
  }
  if (t < 128) ml[t] = mask[j0 + t];

  const int p0 = pb + t;
  const int p1 = pb + 256 + t;
  float4 qa[8], qb[8];
#pragma unroll
  for (int i = 0; i < 8; ++i) {
    qa[i] = *(const float4*)&q_n[(size_t)p0 * 256 + h * 32 + i * 4];
    qb[i] = *(const float4*)&q_n[(size_t)p1 * 256 + h * 32 + i * 4];
  }
  __syncthreads();

  const float cv = ((j0 & 511) < 256) ? 1.f : 0.f;  // tile uniformly fg or bg
  float num0 = 0.f, den0 = 0.f, num1 = 0.f, den1 = 0.f;
  for (int jj = 0; jj < 128; ++jj) {
    float d0 = 0.f, d1 = 0.f;
#pragma unroll
    for (int i = 0; i < 8; ++i) {
      float4 c4 = *(const float4*)&csl[jj * 32 + i * 4];
      d0 += qa[i].x * c4.x + qa[i].y * c4.y + qa[i].z * c4.z + qa[i].w * c4.w;
      d1 += qb[i].x * c4.x + qb[i].y * c4.y + qb[i].z * c4.z + qb[i].w * c4.w;
    }
    float m = ml[jj];
    float e0 = __expf(d0 + m);       // masked -> 0
    float e1 = __expf(d1 + m);
    den0 += e0; den1 += e1;
    num0 += cv * e0; num1 += cv * e1;
  }
  float* o0 = &part[(((size_t)z * 8 + h) * HW + p0) * 2];
  o0[0] = num0; o0[1] = den0;
  float* o1 = &part[(((size_t)z * 8 + h) * HW + p1) * 2];
  o1[0] = num1; o1[1] = den1;
}

// merge 20 key-tile partials: xo[h*HW+p]
__global__ __launch_bounds__(256) void merge_kernel(const float* __restrict__ part,
                                                    float* __restrict__ xo) {
  int idx = blockIdx.x * 256 + threadIdx.x;   // 32768 = h*HW+p
  int h = idx >> 12, p = idx & 4095;
  float n = 0.f, d = 0.f;
#pragma unroll
  for (int z = 0; z < 20; ++z) {
    const float* o = &part[(((size_t)z * 8 + h) * HW + p) * 2];
    n += o[0];
    d += o[1];
  }
  xo[idx] = n / d;
}

// ---------------------------------------------------------------------------
// Conv (cross-correlation) — naive
// ---------------------------------------------------------------------------
template <int CI, int KS, int PAD>
__global__ __launch_bounds__(256) void n_conv(
    const float* __restrict__ in, const float* __restrict__ w,
    const float* __restrict__ b, float* __restrict__ out) {
  const int co = blockIdx.y;
  const int p = blockIdx.x * 256 + threadIdx.x;
  const int y = p >> 6, xx = p & 63;
  float acc = b[co];
  for (int ci = 0; ci < CI; ++ci)
#pragma unroll
    for (int ky = 0; ky < KS; ++ky) {
      int iy = y + ky - PAD;
      if (iy < 0 || iy >= 64) continue;
#pragma unroll
      for (int kx = 0; kx < KS; ++kx) {
        int ix = xx + kx - PAD;
        if (ix < 0 || ix >= 64) continue;
        acc += in[(size_t)ci * HW + iy * 64 + ix] *
               w[(size_t)((co * CI + ci) * KS + ky) * KS + kx];
      }
    }
  out[(size_t)co * HW + p] = acc;
}

// ---------------------------------------------------------------------------
// GroupNorm stats, two-stage.
// ---------------------------------------------------------------------------
__global__ __launch_bounds__(256) void gnstatsA(const float* __restrict__ in,
                                                float* __restrict__ stp, int cpg) {
  __shared__ float sh[256], sh2[256];
  const int g = blockIdx.x, b = blockIdx.y, t = threadIdx.x;
  const int n = cpg * HW;
  const int chunk = n >> 4;
  const float* __restrict__ base = in + (size_t)g * n + (size_t)b * chunk;
  float s = 0.f, ss = 0.f;
  for (int i = t; i < chunk; i += 256) {
    float v = base[i];
    s += v;
    ss += v * v;
  }
  sh[t] = s; sh2[t] = ss;
  __syncthreads();
  for (int w = 128; w > 0; w >>= 1) {
    if (t < w) { sh[t] += sh[t + w]; sh2[t] += sh2[t + w]; }
    __syncthreads();
  }
  if (t == 0) { stp[(g * 16 + b) * 2] = sh[0]; stp[(g * 16 + b) * 2 + 1] = sh2[0]; }
}

__global__ __launch_bounds__(64) void gnstatsB(const float* __restrict__ stp,
                                               float* __restrict__ st, int cpg) {
  const int g = blockIdx.x;
  if (threadIdx.x == 0) {
    float S = 0.f, SS = 0.f;
    for (int b = 0; b < 16; ++b) { S += stp[(g * 16 + b) * 2]; SS += stp[(g * 16 + b) * 2 + 1]; }
    float n = (float)(cpg * HW);
    float mean = S / n;
    float var = SS / n - mean * mean;
    st[g * 2] = mean;
    st[g * 2 + 1] = 1.0f / sqrtf(var + 1e-5f);
  }
}

// GroupNorm apply + ReLU, float32 out (reference output dtype).
__global__ __launch_bounds__(256) void gn_apply(
    const float* __restrict__ in, float* __restrict__ out, const float* __restrict__ st,
    const float* __restrict__ gs, const float* __restrict__ gb, int cpg) {
  const int idx = blockIdx.x * 256 + threadIdx.x;
  const int c = idx >> 12;
  const int g = c / cpg;
  float v = (in[idx] - st[g * 2]) * st[g * 2 + 1] * gs[c] + gb[c];
  out[idx] = fmaxf(v, 0.f);
}

// ---------------------------------------------------------------------------
extern "C" void kernel_launch(void* const* d_in, const int* in_sizes, int n_in,
                              void* d_out, int out_size, void* d_ws, size_t ws_size,
                              hipStream_t stream) {
  const float* x     = (const float*)d_in[0];
  const float* delta = (const float*)d_in[1];
  const float* Wq    = (const float*)d_in[2];
  const float* bq    = (const float*)d_in[3];
  const float* Ws    = (const float*)d_in[4];
  const float* bs    = (const float*)d_in[5];
  const float* scale = (const float*)d_in[6];
  const float* c1w = (const float*)d_in[7],  *c1b = (const float*)d_in[8];
  const float* g1s = (const float*)d_in[9],  *g1b = (const float*)d_in[10];
  const float* c2w = (const float*)d_in[11], *c2b = (const float*)d_in[12];
  const float* g2s = (const float*)d_in[13], *g2b = (const float*)d_in[14];
  const float* c3w = (const float*)d_in[15], *c3b = (const float*)d_in[16];
  const float* g3s = (const float*)d_in[17], *g3b = (const float*)d_in[18];

  float* ws   = (float*)d_ws;
  float* q_n  = ws;                       // 1,048,576
  float* s_n  = q_n + 1048576;            // 5,242,880
  float* c_s  = s_n + 5242880;            //   655,360
  float* mask = c_s + 655360;             //     2,560
  float* xo   = mask + 2560;              //    32,768
  float* st   = xo + 32768;               //        32
  float* stp  = st + 32;                  //       512 (128 used)
  float* un   = stp + 512;                // union: part then conv temps
  float* part = un;                       // 1,310,720 (20*8*4096*2)
  float* t1   = un;                       //    65,536
  float* a1   = un + 65536;               //    65,536
  float* t2   = un + 131072;              //   262,144
  float* a2   = un + 393216;              //   262,144
  float* t3   = un + 655360;              //   524,288
  // total: 6,982,720 + 1,310,720 = 8,293,440 floats ~= 33.2 MB

  proj_kernel<<<dim3(64, 6), 256, 0, stream>>>(x, Wq, bq, Ws, bs, scale, q_n, s_n);
  agg_kernel<<<dim3(256, 5), 256, 0, stream>>>(delta, s_n, c_s, mask);
  attn_kernel<<<dim3(8, 8, 20), 256, 0, stream>>>(q_n, c_s, mask, part);
  merge_kernel<<<128, 256, 0, stream>>>(part, xo);

  n_conv<8, 5, 2><<<dim3(16, 16), 256, 0, stream>>>(xo, c1w, c1b, t1);
  gnstatsA<<<dim3(4, 16), 256, 0, stream>>>(t1, stp, 4);
  gnstatsB<<<4, 64, 0, stream>>>(stp, st, 4);
  gn_apply<<<256, 256, 0, stream>>>(t1, a1, st, g1s, g1b, 4);

  n_conv<16, 3, 1><<<dim3(16, 64), 256, 0, stream>>>(a1, c2w, c2b, t2);
  gnstatsA<<<dim3(4, 16), 256, 0, stream>>>(t2, stp + 128, 16);
  gnstatsB<<<4, 64, 0, stream>>>(stp + 128, st + 8, 16);
  gn_apply<<<1024, 256, 0, stream>>>(t2, a2, st + 8, g2s, g2b, 16);

  n_conv<64, 3, 1><<<dim3(16, 128), 256, 0, stream>>>(a2, c3w, c3b, t3);
  gnstatsA<<<dim3(4, 16), 256, 0, stream>>>(t3, stp + 256, 32);
  gnstatsB<<<4, 64, 0, stream>>>(stp + 256, st + 16, 32);
  gn_apply<<<2048, 256, 0, stream>>>(t3, (float*)d_out, st + 16, g3s, g3b, 32);
}

// Round 15
// 392.137 us; speedup vs baseline: 1.2879x; 1.1906x over previous
//
#include <hip/hip_runtime.h>
#include <hip/hip_bf16.h>
#include <cstddef>

#define HW 4096   // 64*64

// ---------------------------------------------------------------------------
// W transpose: Wt[ci][co] = W[co][ci]  (runs once per W, 256x256 each)
// ---------------------------------------------------------------------------
__global__ __launch_bounds__(256) void wtr_kernel(const float* __restrict__ Wq,
                                                  const float* __restrict__ Ws,
                                                  float* __restrict__ wt) {
  const int ci = blockIdx.x;          // 0..255
  const int w  = blockIdx.y;          // 0=Wq, 1=Ws
  const int co = threadIdx.x;
  const float* __restrict__ W = (w == 0) ? Wq : Ws;
  wt[(size_t)w * 65536 + ci * 256 + co] = W[co * 256 + ci];
}

// ---------------------------------------------------------------------------
// Register-tile projection + fused per-head l2norm.
// grid (64 px-tiles, 4 co-tiles, 6 images), block 256 (16 px-grp x 16 co-grp),
// thread computes 4 px x 4 co. Per ci: 2 LDS b128 -> 16 FMA (FMA-bound).
// ---------------------------------------------------------------------------
__global__ __launch_bounds__(256) void proj_kernel(
    const float* __restrict__ x, const float* __restrict__ wt,
    const float* __restrict__ bq, const float* __restrict__ bs,
    const float* __restrict__ scale,
    float* __restrict__ q_n, float* __restrict__ s_n) {
  const int n   = blockIdx.z;          // image: 0=q, 1..5=s[k]
  const int p0  = blockIdx.x * 64;     // pixel base
  const int co0 = blockIdx.y * 64;     // out-channel base
  const int t   = threadIdx.x;
  const int i   = t & 15;              // px group  (4 px)
  const int j   = t >> 4;              // co group  (4 co)
  const float* __restrict__ Wt = wt + (size_t)(n == 0 ? 0 : 1) * 65536;
  const float* __restrict__ B  = (n == 0) ? bq : bs;

  __shared__ float Xl[16][64];
  __shared__ float Wl[16][64];
  __shared__ float Sl[64][68];         // raw proj staging (pitch 68: 16B-aligned)
  __shared__ float ssl[64][2];         // per (px, head-in-tile) norm

  float acc[4][4];
#pragma unroll
  for (int a = 0; a < 4; ++a)
#pragma unroll
    for (int b = 0; b < 4; ++b) acc[a][b] = 0.f;

  for (int cc = 0; cc < 256; cc += 16) {
    __syncthreads();
#pragma unroll
    for (int pass = 0; pass < 4; ++pass) {
      int ci = pass * 4 + (t >> 6), lane = t & 63;
      Xl[ci][lane] = x[((size_t)n * 256 + cc + ci) * HW + p0 + lane];
      Wl[ci][lane] = Wt[(size_t)(cc + ci) * 256 + co0 + lane];
    }
    __syncthreads();
#pragma unroll
    for (int ci = 0; ci < 16; ++ci) {
      float4 X4 = *(const float4*)&Xl[ci][i * 4];
      float4 W4 = *(const float4*)&Wl[ci][j * 4];
      float xv[4] = {X4.x, X4.y, X4.z, X4.w};
      float wv[4] = {W4.x, W4.y, W4.z, W4.w};
#pragma unroll
      for (int a = 0; a < 4; ++a)
#pragma unroll
        for (int b = 0; b < 4; ++b) acc[a][b] += xv[a] * wv[b];
    }
  }

  // bias, stage raw values
  __syncthreads();
#pragma unroll
  for (int a = 0; a < 4; ++a) {
    float4 v = make_float4(acc[a][0] + B[co0 + j * 4 + 0], acc[a][1] + B[co0 + j * 4 + 1],
                           acc[a][2] + B[co0 + j * 4 + 2], acc[a][3] + B[co0 + j * 4 + 3]);
    *(float4*)&Sl[i * 4 + a][j * 4] = v;
  }
  __syncthreads();

  // per (px, head) sum of squares (heads = co [0,32) and [32,64) of tile)
  if (t < 128) {
    int px = t & 63, hd = t >> 6;
    float ss = 0.f;
#pragma unroll
    for (int dd = 0; dd < 32; ++dd) {
      float v = Sl[px][hd * 32 + dd];
      ss += v * v;
    }
    ssl[px][hd] = fmaxf(sqrtf(ss), 1e-12f);
  }
  __syncthreads();

  // normalized, coalesced write-out
  const float qsc = scale[0] * 0.17677669529663687f;   // scale * HD^-0.5
  float* __restrict__ outp = (n == 0) ? q_n : (s_n + (size_t)(n - 1) * HW * 256);
  const int cin = t & 63, pg = t >> 6;
#pragma unroll
  for (int ii = 0; ii < 16; ++ii) {
    int px = pg * 16 + ii;
    float v = Sl[px][cin] / ssl[px][cin >> 5];
    if (n == 0) v *= qsc;
    outp[(size_t)(p0 + px) * 256 + co0 + cin] = v;
  }
}

// ---------------------------------------------------------------------------
// Patch aggregation -> c_s[8][2560][32], mask[2560] (probe2-verified).
// ---------------------------------------------------------------------------
__global__ __launch_bounds__(256) void agg_kernel(
    const float* __restrict__ delta, const float* __restrict__ s_n,
    float* __restrict__ c_s, float* __restrict__ mask) {
  const int s = blockIdx.x;
  const int k = blockIdx.y;
  const int t = threadIdx.x;
  __shared__ float fgl[16];
  const int sy = (s >> 4) * 4, sx = (s & 15) * 4;
  if (t < 16) {
    int y0 = (sy + (t >> 2)) * 8, x0 = (sx + (t & 3)) * 8;
    fgl[t] = delta[(size_t)k * 512 * 512 + (size_t)y0 * 512 + x0];
  }
  __syncthreads();
  const int h = t >> 5, d = t & 31;
  float af = 0.f, ab = 0.f;
#pragma unroll
  for (int l = 0; l < 16; ++l) {
    int pix = (sy + (l >> 2)) * 64 + sx + (l & 3);
    float sv = s_n[((size_t)k * HW + pix) * 256 + h * 32 + d];
    float f = fgl[l];
    af += f * sv;
    ab += (1.f - f) * sv;
  }
  float ssf = af * af, ssb = ab * ab;
#pragma unroll
  for (int m = 1; m <= 16; m <<= 1) {
    ssf += __shfl_xor(ssf, m);
    ssb += __shfl_xor(ssb, m);
  }
  float vf = af / fmaxf(sqrtf(ssf), 1e-12f);
  float vb = ab / fmaxf(sqrtf(ssb), 1e-12f);
  const int jf = k * 512 + s, jb = jf + 256;
  c_s[((size_t)h * 2560 + jf) * 32 + d] = vf;
  c_s[((size_t)h * 2560 + jb) * 32 + d] = vb;
  if (t == 0) {
    float fs = 0.f;
#pragma unroll
    for (int l = 0; l < 16; ++l) fs += fgl[l];
    mask[jf] = (fs < 1.f) ? -1e30f : 0.f;
    mask[jb] = ((16.f - fs) < 1.f) ? -1e30f : 0.f;
  }
}

// ---------------------------------------------------------------------------
// Attention partials: 2 px/thread, 128-key tiles, 128-thread blocks.
// grid (16 px-tiles of 256, 8 heads, 20 key-tiles) = 2560 blocks.
// ---------------------------------------------------------------------------
__global__ __launch_bounds__(128) void attn_kernel(
    const float* __restrict__ q_n, const float* __restrict__ c_s,
    const float* __restrict__ mask, float* __restrict__ part) {
  const int t = threadIdx.x;           // 0..127
  const int pb = blockIdx.x * 256;
  const int h = blockIdx.y;
  const int z = blockIdx.z;            // key tile (128 keys)
  __shared__ float csl[128 * 32];
  __shared__ float ml[128];
  const int j0 = z * 128;

#pragma unroll
  for (int i = 0; i < 8; ++i) {
    int idx = i * 128 + t;             // 1024 float4s = 128 keys * 8
    int key = idx >> 3, d4 = idx & 7;
    *(float4*)&csl[idx * 4] =
        *(const float4*)&c_s[((size_t)h * 2560 + j0 + key) * 32 + d4 * 4];
  }
  ml[t] = mask[j0 + t];

  const int p0 = pb + t;
  const int p1 = pb + 128 + t;
  float4 qa[8], qb[8];
#pragma unroll
  for (int i = 0; i < 8; ++i) {
    qa[i] = *(const float4*)&q_n[(size_t)p0 * 256 + h * 32 + i * 4];
    qb[i] = *(const float4*)&q_n[(size_t)p1 * 256 + h * 32 + i * 4];
  }
  __syncthreads();

  const float cv = ((j0 & 511) < 256) ? 1.f : 0.f;  // tile uniformly fg or bg
  float num0 = 0.f, den0 = 0.f, num1 = 0.f, den1 = 0.f;
  for (int jj = 0; jj < 128; ++jj) {
    float d0 = 0.f, d1 = 0.f;
#pragma unroll
    for (int i = 0; i < 8; ++i) {
      float4 c4 = *(const float4*)&csl[jj * 32 + i * 4];
      d0 += qa[i].x * c4.x + qa[i].y * c4.y + qa[i].z * c4.z + qa[i].w * c4.w;
      d1 += qb[i].x * c4.x + qb[i].y * c4.y + qb[i].z * c4.z + qb[i].w * c4.w;
    }
    float m = ml[jj];
    float e0 = __expf(d0 + m);         // masked -> 0
    float e1 = __expf(d1 + m);
    den0 += e0; den1 += e1;
    num0 += cv * e0; num1 += cv * e1;
  }
  float* o0 = &part[(((size_t)z * 8 + h) * HW + p0) * 2];
  o0[0] = num0; o0[1] = den0;
  float* o1 = &part[(((size_t)z * 8 + h) * HW + p1) * 2];
  o1[0] = num1; o1[1] = den1;
}

// merge 20 key-tile partials: xo[h*HW+p]
__global__ __launch_bounds__(256) void merge_kernel(const float* __restrict__ part,
                                                    float* __restrict__ xo) {
  int idx = blockIdx.x * 256 + threadIdx.x;   // 32768 = h*HW+p
  int h = idx >> 12, p = idx & 4095;
  float n = 0.f, d = 0.f;
#pragma unroll
  for (int z = 0; z < 20; ++z) {
    const float* o = &part[(((size_t)z * 8 + h) * HW + p) * 2];
    n += o[0];
    d += o[1];
  }
  xo[idx] = n / d;
}

// ---------------------------------------------------------------------------
// Conv (cross-correlation) — naive
// ---------------------------------------------------------------------------
template <int CI, int KS, int PAD>
__global__ __launch_bounds__(256) void n_conv(
    const float* __restrict__ in, const float* __restrict__ w,
    const float* __restrict__ b, float* __restrict__ out) {
  const int co = blockIdx.y;
  const int p = blockIdx.x * 256 + threadIdx.x;
  const int y = p >> 6, xx = p & 63;
  float acc = b[co];
  for (int ci = 0; ci < CI; ++ci)
#pragma unroll
    for (int ky = 0; ky < KS; ++ky) {
      int iy = y + ky - PAD;
      if (iy < 0 || iy >= 64) continue;
#pragma unroll
      for (int kx = 0; kx < KS; ++kx) {
        int ix = xx + kx - PAD;
        if (ix < 0 || ix >= 64) continue;
        acc += in[(size_t)ci * HW + iy * 64 + ix] *
               w[(size_t)((co * CI + ci) * KS + ky) * KS + kx];
      }
    }
  out[(size_t)co * HW + p] = acc;
}

// ---------------------------------------------------------------------------
// GroupNorm stats, two-stage.
// ---------------------------------------------------------------------------
__global__ __launch_bounds__(256) void gnstatsA(const float* __restrict__ in,
                                                float* __restrict__ stp, int cpg) {
  __shared__ float sh[256], sh2[256];
  const int g = blockIdx.x, b = blockIdx.y, t = threadIdx.x;
  const int n = cpg * HW;
  const int chunk = n >> 4;
  const float* __restrict__ base = in + (size_t)g * n + (size_t)b * chunk;
  float s = 0.f, ss = 0.f;
  for (int i = t; i < chunk; i += 256) {
    float v = base[i];
    s += v;
    ss += v * v;
  }
  sh[t] = s; sh2[t] = ss;
  __syncthreads();
  for (int w = 128; w > 0; w >>= 1) {
    if (t < w) { sh[t] += sh[t + w]; sh2[t] += sh2[t + w]; }
    __syncthreads();
  }
  if (t == 0) { stp[(g * 16 + b) * 2] = sh[0]; stp[(g * 16 + b) * 2 + 1] = sh2[0]; }
}

__global__ __launch_bounds__(64) void gnstatsB(const float* __restrict__ stp,
                                               float* __restrict__ st, int cpg) {
  const int g = blockIdx.x;
  if (threadIdx.x == 0) {
    float S = 0.f, SS = 0.f;
    for (int b = 0; b < 16; ++b) { S += stp[(g * 16 + b) * 2]; SS += stp[(g * 16 + b) * 2 + 1]; }
    float n = (float)(cpg * HW);
    float mean = S / n;
    float var = SS / n - mean * mean;
    st[g * 2] = mean;
    st[g * 2 + 1] = 1.0f / sqrtf(var + 1e-5f);
  }
}

// GroupNorm apply + ReLU, float32 out (reference output dtype).
__global__ __launch_bounds__(256) void gn_apply(
    const float* __restrict__ in, float* __restrict__ out, const float* __restrict__ st,
    const float* __restrict__ gs, const float* __restrict__ gb, int cpg) {
  const int idx = blockIdx.x * 256 + threadIdx.x;
  const int c = idx >> 12;
  const int g = c / cpg;
  float v = (in[idx] - st[g * 2]) * st[g * 2 + 1] * gs[c] + gb[c];
  out[idx] = fmaxf(v, 0.f);
}

// ---------------------------------------------------------------------------
extern "C" void kernel_launch(void* const* d_in, const int* in_sizes, int n_in,
                              void* d_out, int out_size, void* d_ws, size_t ws_size,
                              hipStream_t stream) {
  const float* x     = (const float*)d_in[0];
  const float* delta = (const float*)d_in[1];
  const float* Wq    = (const float*)d_in[2];
  const float* bq    = (const float*)d_in[3];
  const float* Ws    = (const float*)d_in[4];
  const float* bs    = (const float*)d_in[5];
  const float* scale = (const float*)d_in[6];
  const float* c1w = (const float*)d_in[7],  *c1b = (const float*)d_in[8];
  const float* g1s = (const float*)d_in[9],  *g1b = (const float*)d_in[10];
  const float* c2w = (const float*)d_in[11], *c2b = (const float*)d_in[12];
  const float* g2s = (const float*)d_in[13], *g2b = (const float*)d_in[14];
  const float* c3w = (const float*)d_in[15], *c3b = (const float*)d_in[16];
  const float* g3s = (const float*)d_in[17], *g3b = (const float*)d_in[18];

  float* ws   = (float*)d_ws;
  float* q_n  = ws;                       // 1,048,576
  float* s_n  = q_n + 1048576;            // 5,242,880
  float* c_s  = s_n + 5242880;            //   655,360
  float* mask = c_s + 655360;             //     2,560
  float* xo   = mask + 2560;              //    32,768
  float* st   = xo + 32768;               //        32
  float* stp  = st + 32;                  //       512 (128 used)
  float* wt   = stp + 512;                //   131,072 (2 x 256 x 256)
  float* un   = wt + 131072;              // union: part then conv temps
  float* part = un;                       // 1,310,720 (20*8*4096*2)
  float* t1   = un;                       //    65,536
  float* a1   = un + 65536;               //    65,536
  float* t2   = un + 131072;              //   262,144
  float* a2   = un + 393216;              //   262,144
  float* t3   = un + 655360;              //   524,288
  // total: 8,424,480 floats ~= 33.7 MB (< 34.1 MB verified floor)

  wtr_kernel<<<dim3(256, 2), 256, 0, stream>>>(Wq, Ws, wt);
  proj_kernel<<<dim3(64, 4, 6), 256, 0, stream>>>(x, wt, bq, bs, scale, q_n, s_n);
  agg_kernel<<<dim3(256, 5), 256, 0, stream>>>(delta, s_n, c_s, mask);
  attn_kernel<<<dim3(16, 8, 20), 128, 0, stream>>>(q_n, c_s, mask, part);
  merge_kernel<<<128, 256, 0, stream>>>(part, xo);

  n_conv<8, 5, 2><<<dim3(16, 16), 256, 0, stream>>>(xo, c1w, c1b, t1);
  gnstatsA<<<dim3(4, 16), 256, 0, stream>>>(t1, stp, 4);
  gnstatsB<<<4, 64, 0, stream>>>(stp, st, 4);
  gn_apply<<<256, 256, 0, stream>>>(t1, a1, st, g1s, g1b, 4);

  n_conv<16, 3, 1><<<dim3(16, 64), 256, 0, stream>>>(a1, c2w, c2b, t2);
  gnstatsA<<<dim3(4, 16), 256, 0, stream>>>(t2, stp + 128, 16);
  gnstatsB<<<4, 64, 0, stream>>>(stp + 128, st + 8, 16);
  gn_apply<<<1024, 256, 0, stream>>>(t2, a2, st + 8, g2s, g2b, 16);

  n_conv<64, 3, 1><<<dim3(16, 128), 256, 0, stream>>>(a2, c3w, c3b, t3);
  gnstatsA<<<dim3(4, 16), 256, 0, stream>>>(t3, stp + 256, 32);
  gnstatsB<<<4, 64, 0, stream>>>(stp + 256, st + 16, 32);
  gn_apply<<<2048, 256, 0, stream>>>(t3, (float*)d_out, st + 16, g3s, g3b, 32);
}

// Round 16
// 315.032 us; speedup vs baseline: 1.6032x; 1.2448x over previous
//
#include <hip/hip_runtime.h>
#include <hip/hip_bf16.h>
#include <cstddef>

#define HW 4096   // 64*64

// ---------------------------------------------------------------------------
// W transpose: Wt[ci][co] = W[co][ci]
// ---------------------------------------------------------------------------
__global__ __launch_bounds__(256) void wtr_kernel(const float* __restrict__ Wq,
                                                  const float* __restrict__ Ws,
                                                  float* __restrict__ wt) {
  const int ci = blockIdx.x;
  const int w  = blockIdx.y;
  const int co = threadIdx.x;
  const float* __restrict__ W = (w == 0) ? Wq : Ws;
  wt[(size_t)w * 65536 + ci * 256 + co] = W[co * 256 + ci];
}

// ---------------------------------------------------------------------------
// Register-tile projection + fused per-head l2norm (round-15, verified).
// ---------------------------------------------------------------------------
__global__ __launch_bounds__(256) void proj_kernel(
    const float* __restrict__ x, const float* __restrict__ wt,
    const float* __restrict__ bq, const float* __restrict__ bs,
    const float* __restrict__ scale,
    float* __restrict__ q_n, float* __restrict__ s_n) {
  const int n   = blockIdx.z;
  const int p0  = blockIdx.x * 64;
  const int co0 = blockIdx.y * 64;
  const int t   = threadIdx.x;
  const int i   = t & 15;
  const int j   = t >> 4;
  const float* __restrict__ Wt = wt + (size_t)(n == 0 ? 0 : 1) * 65536;
  const float* __restrict__ B  = (n == 0) ? bq : bs;

  __shared__ float Xl[16][64];
  __shared__ float Wl[16][64];
  __shared__ float Sl[64][68];
  __shared__ float ssl[64][2];

  float acc[4][4];
#pragma unroll
  for (int a = 0; a < 4; ++a)
#pragma unroll
    for (int b = 0; b < 4; ++b) acc[a][b] = 0.f;

  for (int cc = 0; cc < 256; cc += 16) {
    __syncthreads();
#pragma unroll
    for (int pass = 0; pass < 4; ++pass) {
      int ci = pass * 4 + (t >> 6), lane = t & 63;
      Xl[ci][lane] = x[((size_t)n * 256 + cc + ci) * HW + p0 + lane];
      Wl[ci][lane] = Wt[(size_t)(cc + ci) * 256 + co0 + lane];
    }
    __syncthreads();
#pragma unroll
    for (int ci = 0; ci < 16; ++ci) {
      float4 X4 = *(const float4*)&Xl[ci][i * 4];
      float4 W4 = *(const float4*)&Wl[ci][j * 4];
      float xv[4] = {X4.x, X4.y, X4.z, X4.w};
      float wv[4] = {W4.x, W4.y, W4.z, W4.w};
#pragma unroll
      for (int a = 0; a < 4; ++a)
#pragma unroll
        for (int b = 0; b < 4; ++b) acc[a][b] += xv[a] * wv[b];
    }
  }

  __syncthreads();
#pragma unroll
  for (int a = 0; a < 4; ++a) {
    float4 v = make_float4(acc[a][0] + B[co0 + j * 4 + 0], acc[a][1] + B[co0 + j * 4 + 1],
                           acc[a][2] + B[co0 + j * 4 + 2], acc[a][3] + B[co0 + j * 4 + 3]);
    *(float4*)&Sl[i * 4 + a][j * 4] = v;
  }
  __syncthreads();

  if (t < 128) {
    int px = t & 63, hd = t >> 6;
    float ss = 0.f;
#pragma unroll
    for (int dd = 0; dd < 32; ++dd) {
      float v = Sl[px][hd * 32 + dd];
      ss += v * v;
    }
    ssl[px][hd] = fmaxf(sqrtf(ss), 1e-12f);
  }
  __syncthreads();

  const float qsc = scale[0] * 0.17677669529663687f;
  float* __restrict__ outp = (n == 0) ? q_n : (s_n + (size_t)(n - 1) * HW * 256);
  const int cin = t & 63, pg = t >> 6;
#pragma unroll
  for (int ii = 0; ii < 16; ++ii) {
    int px = pg * 16 + ii;
    float v = Sl[px][cin] / ssl[px][cin >> 5];
    if (n == 0) v *= qsc;
    outp[(size_t)(p0 + px) * 256 + co0 + cin] = v;
  }
}

// ---------------------------------------------------------------------------
// Patch aggregation -> c_s[8][2560][32], mask[2560] (probe2-verified).
// ---------------------------------------------------------------------------
__global__ __launch_bounds__(256) void agg_kernel(
    const float* __restrict__ delta, const float* __restrict__ s_n,
    float* __restrict__ c_s, float* __restrict__ mask) {
  const int s = blockIdx.x;
  const int k = blockIdx.y;
  const int t = threadIdx.x;
  __shared__ float fgl[16];
  const int sy = (s >> 4) * 4, sx = (s & 15) * 4;
  if (t < 16) {
    int y0 = (sy + (t >> 2)) * 8, x0 = (sx + (t & 3)) * 8;
    fgl[t] = delta[(size_t)k * 512 * 512 + (size_t)y0 * 512 + x0];
  }
  __syncthreads();
  const int h = t >> 5, d = t & 31;
  float af = 0.f, ab = 0.f;
#pragma unroll
  for (int l = 0; l < 16; ++l) {
    int pix = (sy + (l >> 2)) * 64 + sx + (l & 3);
    float sv = s_n[((size_t)k * HW + pix) * 256 + h * 32 + d];
    float f = fgl[l];
    af += f * sv;
    ab += (1.f - f) * sv;
  }
  float ssf = af * af, ssb = ab * ab;
#pragma unroll
  for (int m = 1; m <= 16; m <<= 1) {
    ssf += __shfl_xor(ssf, m);
    ssb += __shfl_xor(ssb, m);
  }
  float vf = af / fmaxf(sqrtf(ssf), 1e-12f);
  float vb = ab / fmaxf(sqrtf(ssb), 1e-12f);
  const int jf = k * 512 + s, jb = jf + 256;
  c_s[((size_t)h * 2560 + jf) * 32 + d] = vf;
  c_s[((size_t)h * 2560 + jb) * 32 + d] = vb;
  if (t == 0) {
    float fs = 0.f;
#pragma unroll
    for (int l = 0; l < 16; ++l) fs += fgl[l];
    mask[jf] = (fs < 1.f) ? -1e30f : 0.f;
    mask[jb] = ((16.f - fs) < 1.f) ? -1e30f : 0.f;
  }
}

// ---------------------------------------------------------------------------
// Attention as outer-product GEMM tile: block = 64 px x 128 keys,
// thread = 4 px x 8 keys (32 independent FMA chains).
// grid (64 px-tiles, 8 heads, 20 key-tiles). LDS ~30KB.
// ---------------------------------------------------------------------------
__global__ __launch_bounds__(256) void attn_kernel(
    const float* __restrict__ q_n, const float* __restrict__ c_s,
    const float* __restrict__ mask, float* __restrict__ part) {
  const int t  = threadIdx.x;
  const int p0 = blockIdx.x * 64;
  const int h  = blockIdx.y;
  const int z  = blockIdx.z;
  const int j0 = z * 128;

  __shared__ float Qt[32][68];    // [d][px]
  __shared__ float Ct[32][132];   // [d][key]
  __shared__ float red[16][64];   // [key-group][px]
  __shared__ float ml[128];

  // stage Q transposed: Qt[d][px] = q_n[(p0+px)*256 + h*32 + d]
#pragma unroll
  for (int pass = 0; pass < 2; ++pass) {
    int idx = pass * 256 + t;                 // 512 float4 = 64 px * 8 d-grps
    int px = idx >> 3, d4 = idx & 7;
    float4 v = *(const float4*)&q_n[(size_t)(p0 + px) * 256 + h * 32 + d4 * 4];
    Qt[d4 * 4 + 0][px] = v.x;
    Qt[d4 * 4 + 1][px] = v.y;
    Qt[d4 * 4 + 2][px] = v.z;
    Qt[d4 * 4 + 3][px] = v.w;
  }
  // stage C transposed: Ct[d][jj] = c_s[(h*2560 + j0+jj)*32 + d]
#pragma unroll
  for (int pass = 0; pass < 4; ++pass) {
    int idx = pass * 256 + t;                 // 1024 float4 = 128 key * 8
    int jj = idx >> 3, d4 = idx & 7;
    float4 v = *(const float4*)&c_s[((size_t)h * 2560 + j0 + jj) * 32 + d4 * 4];
    Ct[d4 * 4 + 0][jj] = v.x;
    Ct[d4 * 4 + 1][jj] = v.y;
    Ct[d4 * 4 + 2][jj] = v.z;
    Ct[d4 * 4 + 3][jj] = v.w;
  }
  if (t < 128) ml[t] = mask[j0 + t];
  __syncthreads();

  const int i = t & 15;    // px group:  px  = i*4 + a
  const int j = t >> 4;    // key group: key = j*8 + b
  float acc[4][8];
#pragma unroll
  for (int a = 0; a < 4; ++a)
#pragma unroll
    for (int b = 0; b < 8; ++b) acc[a][b] = 0.f;

#pragma unroll
  for (int d = 0; d < 32; ++d) {
    float4 q4  = *(const float4*)&Qt[d][i * 4];
    float4 c40 = *(const float4*)&Ct[d][j * 8];
    float4 c41 = *(const float4*)&Ct[d][j * 8 + 4];
    float qv[4] = {q4.x, q4.y, q4.z, q4.w};
    float cw[8] = {c40.x, c40.y, c40.z, c40.w, c41.x, c41.y, c41.z, c41.w};
#pragma unroll
    for (int a = 0; a < 4; ++a)
#pragma unroll
      for (int b = 0; b < 8; ++b) acc[a][b] += qv[a] * cw[b];
  }

  // exp + mask, per-thread row sums over 8 keys
  float rsum[4];
#pragma unroll
  for (int a = 0; a < 4; ++a) {
    float s = 0.f;
#pragma unroll
    for (int b = 0; b < 8; ++b) s += __expf(acc[a][b] + ml[j * 8 + b]);
    rsum[a] = s;
  }
#pragma unroll
  for (int a = 0; a < 4; ++a) red[j][i * 4 + a] = rsum[a];
  __syncthreads();

  if (t < 64) {
    float den = 0.f;
#pragma unroll
    for (int jg = 0; jg < 16; ++jg) den += red[jg][t];
    const float cv = ((j0 & 511) < 256) ? 1.f : 0.f;   // tile uniform fg/bg
    float* o = &part[(((size_t)z * 8 + h) * HW + p0 + t) * 2];
    o[0] = cv * den;
    o[1] = den;
  }
}

// merge 20 key-tile partials: xo[h*HW+p]
__global__ __launch_bounds__(256) void merge_kernel(const float* __restrict__ part,
                                                    float* __restrict__ xo) {
  int idx = blockIdx.x * 256 + threadIdx.x;   // 32768 = h*HW+p
  int h = idx >> 12, p = idx & 4095;
  float n = 0.f, d = 0.f;
#pragma unroll
  for (int z = 0; z < 20; ++z) {
    const float* o = &part[(((size_t)z * 8 + h) * HW + p) * 2];
    n += o[0];
    d += o[1];
  }
  xo[idx] = n / d;
}

// ---------------------------------------------------------------------------
// Conv (cross-correlation) — naive
// ---------------------------------------------------------------------------
template <int CI, int KS, int PAD>
__global__ __launch_bounds__(256) void n_conv(
    const float* __restrict__ in, const float* __restrict__ w,
    const float* __restrict__ b, float* __restrict__ out) {
  const int co = blockIdx.y;
  const int p = blockIdx.x * 256 + threadIdx.x;
  const int y = p >> 6, xx = p & 63;
  float acc = b[co];
  for (int ci = 0; ci < CI; ++ci)
#pragma unroll
    for (int ky = 0; ky < KS; ++ky) {
      int iy = y + ky - PAD;
      if (iy < 0 || iy >= 64) continue;
#pragma unroll
      for (int kx = 0; kx < KS; ++kx) {
        int ix = xx + kx - PAD;
        if (ix < 0 || ix >= 64) continue;
        acc += in[(size_t)ci * HW + iy * 64 + ix] *
               w[(size_t)((co * CI + ci) * KS + ky) * KS + kx];
      }
    }
  out[(size_t)co * HW + p] = acc;
}

// ---------------------------------------------------------------------------
// GroupNorm stats, two-stage.
// ---------------------------------------------------------------------------
__global__ __launch_bounds__(256) void gnstatsA(const float* __restrict__ in,
                                                float* __restrict__ stp, int cpg) {
  __shared__ float sh[256], sh2[256];
  const int g = blockIdx.x, b = blockIdx.y, t = threadIdx.x;
  const int n = cpg * HW;
  const int chunk = n >> 4;
  const float* __restrict__ base = in + (size_t)g * n + (size_t)b * chunk;
  float s = 0.f, ss = 0.f;
  for (int i = t; i < chunk; i += 256) {
    float v = base[i];
    s += v;
    ss += v * v;
  }
  sh[t] = s; sh2[t] = ss;
  __syncthreads();
  for (int w = 128; w > 0; w >>= 1) {
    if (t < w) { sh[t] += sh[t + w]; sh2[t] += sh2[t + w]; }
    __syncthreads();
  }
  if (t == 0) { stp[(g * 16 + b) * 2] = sh[0]; stp[(g * 16 + b) * 2 + 1] = sh2[0]; }
}

__global__ __launch_bounds__(64) void gnstatsB(const float* __restrict__ stp,
                                               float* __restrict__ st, int cpg) {
  const int g = blockIdx.x;
  if (threadIdx.x == 0) {
    float S = 0.f, SS = 0.f;
    for (int b = 0; b < 16; ++b) { S += stp[(g * 16 + b) * 2]; SS += stp[(g * 16 + b) * 2 + 1]; }
    float n = (float)(cpg * HW);
    float mean = S / n;
    float var = SS / n - mean * mean;
    st[g * 2] = mean;
    st[g * 2 + 1] = 1.0f / sqrtf(var + 1e-5f);
  }
}

// GroupNorm apply + ReLU, float32 out (reference output dtype).
__global__ __launch_bounds__(256) void gn_apply(
    const float* __restrict__ in, float* __restrict__ out, const float* __restrict__ st,
    const float* __restrict__ gs, const float* __restrict__ gb, int cpg) {
  const int idx = blockIdx.x * 256 + threadIdx.x;
  const int c = idx >> 12;
  const int g = c / cpg;
  float v = (in[idx] - st[g * 2]) * st[g * 2 + 1] * gs[c] + gb[c];
  out[idx] = fmaxf(v, 0.f);
}

// ---------------------------------------------------------------------------
extern "C" void kernel_launch(void* const* d_in, const int* in_sizes, int n_in,
                              void* d_out, int out_size, void* d_ws, size_t ws_size,
                              hipStream_t stream) {
  const float* x     = (const float*)d_in[0];
  const float* delta = (const float*)d_in[1];
  const float* Wq    = (const float*)d_in[2];
  const float* bq    = (const float*)d_in[3];
  const float* Ws    = (const float*)d_in[4];
  const float* bs    = (const float*)d_in[5];
  const float* scale = (const float*)d_in[6];
  const float* c1w = (const float*)d_in[7],  *c1b = (const float*)d_in[8];
  const float* g1s = (const float*)d_in[9],  *g1b = (const float*)d_in[10];
  const float* c2w = (const float*)d_in[11], *c2b = (const float*)d_in[12];
  const float* g2s = (const float*)d_in[13], *g2b = (const float*)d_in[14];
  const float* c3w = (const float*)d_in[15], *c3b = (const float*)d_in[16];
  const float* g3s = (const float*)d_in[17], *g3b = (const float*)d_in[18];

  float* ws   = (float*)d_ws;
  float* q_n  = ws;                       // 1,048,576
  float* s_n  = q_n + 1048576;            // 5,242,880
  float* c_s  = s_n + 5242880;            //   655,360
  float* mask = c_s + 655360;             //     2,560
  float* xo   = mask + 2560;              //    32,768
  float* st   = xo + 32768;               //        32
  float* stp  = st + 32;                  //       512 (128 used)
  float* wt   = stp + 512;                //   131,072
  float* un   = wt + 131072;              // union: part then conv temps
  float* part = un;                       // 1,310,720 (20*8*4096*2)
  float* t1   = un;                       //    65,536
  float* a1   = un + 65536;               //    65,536
  float* t2   = un + 131072;              //   262,144
  float* a2   = un + 393216;              //   262,144
  float* t3   = un + 655360;              //   524,288
  // total: 8,424,480 floats ~= 33.7 MB (same as round 15, proven fit)

  wtr_kernel<<<dim3(256, 2), 256, 0, stream>>>(Wq, Ws, wt);
  proj_kernel<<<dim3(64, 4, 6), 256, 0, stream>>>(x, wt, bq, bs, scale, q_n, s_n);
  agg_kernel<<<dim3(256, 5), 256, 0, stream>>>(delta, s_n, c_s, mask);
  attn_kernel<<<dim3(64, 8, 20), 256, 0, stream>>>(q_n, c_s, mask, part);
  merge_kernel<<<128, 256, 0, stream>>>(part, xo);

  n_conv<8, 5, 2><<<dim3(16, 16), 256, 0, stream>>>(xo, c1w, c1b, t1);
  gnstatsA<<<dim3(4, 16), 256, 0, stream>>>(t1, stp, 4);
  gnstatsB<<<4, 64, 0, stream>>>(stp, st, 4);
  gn_apply<<<256, 256, 0, stream>>>(t1, a1, st, g1s, g1b, 4);

  n_conv<16, 3, 1><<<dim3(16, 64), 256, 0, stream>>>(a1, c2w, c2b, t2);
  gnstatsA<<<dim3(4, 16), 256, 0, stream>>>(t2, stp + 128, 16);
  gnstatsB<<<4, 64, 0, stream>>>(stp + 128, st + 8, 16);
  gn_apply<<<1024, 256, 0, stream>>>(t2, a2, st + 8, g2s, g2b, 16);

  n_conv<64, 3, 1><<<dim3(16, 128), 256, 0, stream>>>(a2, c3w, c3b, t3);
  gnstatsA<<<dim3(4, 16), 256, 0, stream>>>(t3, stp + 256, 32);
  gnstatsB<<<4, 64, 0, stream>>>(stp + 256, st + 16, 32);
  gn_apply<<<2048, 256, 0, stream>>>(t3, (float*)d_out, st + 16, g3s, g3b, 32);
}

// Round 17
// 270.238 us; speedup vs baseline: 1.8689x; 1.1658x over previous
//
#include <hip/hip_runtime.h>
#include <hip/hip_bf16.h>
#include <cstddef>

#define HW 4096   // 64*64

// ---------------------------------------------------------------------------
// W transpose: Wt[ci][co] = W[co][ci]
// ---------------------------------------------------------------------------
__global__ __launch_bounds__(256) void wtr_kernel(const float* __restrict__ Wq,
                                                  const float* __restrict__ Ws,
                                                  float* __restrict__ wt) {
  const int ci = blockIdx.x;
  const int w  = blockIdx.y;
  const int co = threadIdx.x;
  const float* __restrict__ W = (w == 0) ? Wq : Ws;
  wt[(size_t)w * 65536 + ci * 256 + co] = W[co * 256 + ci];
}

// ---------------------------------------------------------------------------
// Register-tile projection + fused per-head l2norm (verified, round 15/16).
// ---------------------------------------------------------------------------
__global__ __launch_bounds__(256) void proj_kernel(
    const float* __restrict__ x, const float* __restrict__ wt,
    const float* __restrict__ bq, const float* __restrict__ bs,
    const float* __restrict__ scale,
    float* __restrict__ q_n, float* __restrict__ s_n) {
  const int n   = blockIdx.z;
  const int p0  = blockIdx.x * 64;
  const int co0 = blockIdx.y * 64;
  const int t   = threadIdx.x;
  const int i   = t & 15;
  const int j   = t >> 4;
  const float* __restrict__ Wt = wt + (size_t)(n == 0 ? 0 : 1) * 65536;
  const float* __restrict__ B  = (n == 0) ? bq : bs;

  __shared__ float Xl[16][64];
  __shared__ float Wl[16][64];
  __shared__ float Sl[64][68];
  __shared__ float ssl[64][2];

  float acc[4][4];
#pragma unroll
  for (int a = 0; a < 4; ++a)
#pragma unroll
    for (int b = 0; b < 4; ++b) acc[a][b] = 0.f;

  for (int cc = 0; cc < 256; cc += 16) {
    __syncthreads();
#pragma unroll
    for (int pass = 0; pass < 4; ++pass) {
      int ci = pass * 4 + (t >> 6), lane = t & 63;
      Xl[ci][lane] = x[((size_t)n * 256 + cc + ci) * HW + p0 + lane];
      Wl[ci][lane] = Wt[(size_t)(cc + ci) * 256 + co0 + lane];
    }
    __syncthreads();
#pragma unroll
    for (int ci = 0; ci < 16; ++ci) {
      float4 X4 = *(const float4*)&Xl[ci][i * 4];
      float4 W4 = *(const float4*)&Wl[ci][j * 4];
      float xv[4] = {X4.x, X4.y, X4.z, X4.w};
      float wv[4] = {W4.x, W4.y, W4.z, W4.w};
#pragma unroll
      for (int a = 0; a < 4; ++a)
#pragma unroll
        for (int b = 0; b < 4; ++b) acc[a][b] += xv[a] * wv[b];
    }
  }

  __syncthreads();
#pragma unroll
  for (int a = 0; a < 4; ++a) {
    float4 v = make_float4(acc[a][0] + B[co0 + j * 4 + 0], acc[a][1] + B[co0 + j * 4 + 1],
                           acc[a][2] + B[co0 + j * 4 + 2], acc[a][3] + B[co0 + j * 4 + 3]);
    *(float4*)&Sl[i * 4 + a][j * 4] = v;
  }
  __syncthreads();

  if (t < 128) {
    int px = t & 63, hd = t >> 6;
    float ss = 0.f;
#pragma unroll
    for (int dd = 0; dd < 32; ++dd) {
      float v = Sl[px][hd * 32 + dd];
      ss += v * v;
    }
    ssl[px][hd] = fmaxf(sqrtf(ss), 1e-12f);
  }
  __syncthreads();

  const float qsc = scale[0] * 0.17677669529663687f;
  float* __restrict__ outp = (n == 0) ? q_n : (s_n + (size_t)(n - 1) * HW * 256);
  const int cin = t & 63, pg = t >> 6;
#pragma unroll
  for (int ii = 0; ii < 16; ++ii) {
    int px = pg * 16 + ii;
    float v = Sl[px][cin] / ssl[px][cin >> 5];
    if (n == 0) v *= qsc;
    outp[(size_t)(p0 + px) * 256 + co0 + cin] = v;
  }
}

// ---------------------------------------------------------------------------
// Patch aggregation -> c_s[8][2560][32], mask[2560] (probe2-verified).
// ---------------------------------------------------------------------------
__global__ __launch_bounds__(256) void agg_kernel(
    const float* __restrict__ delta, const float* __restrict__ s_n,
    float* __restrict__ c_s, float* __restrict__ mask) {
  const int s = blockIdx.x;
  const int k = blockIdx.y;
  const int t = threadIdx.x;
  __shared__ float fgl[16];
  const int sy = (s >> 4) * 4, sx = (s & 15) * 4;
  if (t < 16) {
    int y0 = (sy + (t >> 2)) * 8, x0 = (sx + (t & 3)) * 8;
    fgl[t] = delta[(size_t)k * 512 * 512 + (size_t)y0 * 512 + x0];
  }
  __syncthreads();
  const int h = t >> 5, d = t & 31;
  float af = 0.f, ab = 0.f;
#pragma unroll
  for (int l = 0; l < 16; ++l) {
    int pix = (sy + (l >> 2)) * 64 + sx + (l & 3);
    float sv = s_n[((size_t)k * HW + pix) * 256 + h * 32 + d];
    float f = fgl[l];
    af += f * sv;
    ab += (1.f - f) * sv;
  }
  float ssf = af * af, ssb = ab * ab;
#pragma unroll
  for (int m = 1; m <= 16; m <<= 1) {
    ssf += __shfl_xor(ssf, m);
    ssb += __shfl_xor(ssb, m);
  }
  float vf = af / fmaxf(sqrtf(ssf), 1e-12f);
  float vb = ab / fmaxf(sqrtf(ssb), 1e-12f);
  const int jf = k * 512 + s, jb = jf + 256;
  c_s[((size_t)h * 2560 + jf) * 32 + d] = vf;
  c_s[((size_t)h * 2560 + jb) * 32 + d] = vb;
  if (t == 0) {
    float fs = 0.f;
#pragma unroll
    for (int l = 0; l < 16; ++l) fs += fgl[l];
    mask[jf] = (fs < 1.f) ? -1e30f : 0.f;
    mask[jb] = ((16.f - fs) < 1.f) ? -1e30f : 0.f;
  }
}

// ---------------------------------------------------------------------------
// Attention outer-product tile (verified, round 16).
// ---------------------------------------------------------------------------
__global__ __launch_bounds__(256) void attn_kernel(
    const float* __restrict__ q_n, const float* __restrict__ c_s,
    const float* __restrict__ mask, float* __restrict__ part) {
  const int t  = threadIdx.x;
  const int p0 = blockIdx.x * 64;
  const int h  = blockIdx.y;
  const int z  = blockIdx.z;
  const int j0 = z * 128;

  __shared__ float Qt[32][68];
  __shared__ float Ct[32][132];
  __shared__ float red[16][64];
  __shared__ float ml[128];

#pragma unroll
  for (int pass = 0; pass < 2; ++pass) {
    int idx = pass * 256 + t;
    int px = idx >> 3, d4 = idx & 7;
    float4 v = *(const float4*)&q_n[(size_t)(p0 + px) * 256 + h * 32 + d4 * 4];
    Qt[d4 * 4 + 0][px] = v.x;
    Qt[d4 * 4 + 1][px] = v.y;
    Qt[d4 * 4 + 2][px] = v.z;
    Qt[d4 * 4 + 3][px] = v.w;
  }
#pragma unroll
  for (int pass = 0; pass < 4; ++pass) {
    int idx = pass * 256 + t;
    int jj = idx >> 3, d4 = idx & 7;
    float4 v = *(const float4*)&c_s[((size_t)h * 2560 + j0 + jj) * 32 + d4 * 4];
    Ct[d4 * 4 + 0][jj] = v.x;
    Ct[d4 * 4 + 1][jj] = v.y;
    Ct[d4 * 4 + 2][jj] = v.z;
    Ct[d4 * 4 + 3][jj] = v.w;
  }
  if (t < 128) ml[t] = mask[j0 + t];
  __syncthreads();

  const int i = t & 15;
  const int j = t >> 4;
  float acc[4][8];
#pragma unroll
  for (int a = 0; a < 4; ++a)
#pragma unroll
    for (int b = 0; b < 8; ++b) acc[a][b] = 0.f;

#pragma unroll
  for (int d = 0; d < 32; ++d) {
    float4 q4  = *(const float4*)&Qt[d][i * 4];
    float4 c40 = *(const float4*)&Ct[d][j * 8];
    float4 c41 = *(const float4*)&Ct[d][j * 8 + 4];
    float qv[4] = {q4.x, q4.y, q4.z, q4.w};
    float cw[8] = {c40.x, c40.y, c40.z, c40.w, c41.x, c41.y, c41.z, c41.w};
#pragma unroll
    for (int a = 0; a < 4; ++a)
#pragma unroll
      for (int b = 0; b < 8; ++b) acc[a][b] += qv[a] * cw[b];
  }

  float rsum[4];
#pragma unroll
  for (int a = 0; a < 4; ++a) {
    float s = 0.f;
#pragma unroll
    for (int b = 0; b < 8; ++b) s += __expf(acc[a][b] + ml[j * 8 + b]);
    rsum[a] = s;
  }
#pragma unroll
  for (int a = 0; a < 4; ++a) red[j][i * 4 + a] = rsum[a];
  __syncthreads();

  if (t < 64) {
    float den = 0.f;
#pragma unroll
    for (int jg = 0; jg < 16; ++jg) den += red[jg][t];
    const float cv = ((j0 & 511) < 256) ? 1.f : 0.f;
    float* o = &part[(((size_t)z * 8 + h) * HW + p0 + t) * 2];
    o[0] = cv * den;
    o[1] = den;
  }
}

// merge 20 key-tile partials: xo[h*HW+p]
__global__ __launch_bounds__(256) void merge_kernel(const float* __restrict__ part,
                                                    float* __restrict__ xo) {
  int idx = blockIdx.x * 256 + threadIdx.x;
  int h = idx >> 12, p = idx & 4095;
  float n = 0.f, d = 0.f;
#pragma unroll
  for (int z = 0; z < 20; ++z) {
    const float* o = &part[(((size_t)z * 8 + h) * HW + p) * 2];
    n += o[0];
    d += o[1];
  }
  xo[idx] = n / d;
}

// ---------------------------------------------------------------------------
// LDS-staged register-tiled conv. Block = 4x64 px tile x COT cos.
// Thread = 1 px, COT independent acc chains. X patch + W staged in LDS.
// ---------------------------------------------------------------------------
template <int CI, int CIC, int KS, int PAD, int COT>
__global__ __launch_bounds__(256) void conv_tile(
    const float* __restrict__ in, const float* __restrict__ w,
    const float* __restrict__ b, float* __restrict__ out) {
  constexpr int R = 4 + KS - 1;
  constexpr int C = 64 + 2 * PAD;
  const int t   = threadIdx.x;
  const int y0  = blockIdx.x * 4;
  const int co0 = blockIdx.y * COT;

  __shared__ float Xl[CIC][R][C];
  __shared__ float Wl[CIC][KS * KS][COT];

  const int xi = t & 63;
  const int yr = t >> 6;

  float acc[COT];
#pragma unroll
  for (int c = 0; c < COT; ++c) acc[c] = b[co0 + c];

  for (int cb = 0; cb < CI; cb += CIC) {
    __syncthreads();
    // stage X patch (zero-padded)
    for (int idx = t; idx < CIC * R * C; idx += 256) {
      int ci = idx / (R * C), rem = idx % (R * C), pr = rem / C, pc = rem % C;
      int iy = y0 + pr - PAD, ix = pc - PAD;
      float v = 0.f;
      if (iy >= 0 && iy < 64 && ix >= 0 && ix < 64)
        v = in[(size_t)(cb + ci) * HW + iy * 64 + ix];
      Xl[ci][pr][pc] = v;
    }
    // stage W
    for (int idx = t; idx < CIC * KS * KS * COT; idx += 256) {
      int ci = idx / (KS * KS * COT), rem = idx % (KS * KS * COT);
      int kk = rem / COT, c = rem % COT;
      Wl[ci][kk][c] = w[(size_t)((co0 + c) * CI + cb + ci) * KS * KS + kk];
    }
    __syncthreads();
#pragma unroll
    for (int ci = 0; ci < CIC; ++ci)
#pragma unroll
      for (int ky = 0; ky < KS; ++ky)
#pragma unroll
        for (int kx = 0; kx < KS; ++kx) {
          float xv = Xl[ci][yr + ky][xi + kx];
          const float4* w4 = (const float4*)&Wl[ci][ky * KS + kx][0];
#pragma unroll
          for (int c4 = 0; c4 < COT / 4; ++c4) {
            float4 wv = w4[c4];
            acc[c4 * 4 + 0] += xv * wv.x;
            acc[c4 * 4 + 1] += xv * wv.y;
            acc[c4 * 4 + 2] += xv * wv.z;
            acc[c4 * 4 + 3] += xv * wv.w;
          }
        }
  }
  const int p = (y0 + yr) * 64 + xi;
#pragma unroll
  for (int c = 0; c < COT; ++c)
    out[(size_t)(co0 + c) * HW + p] = acc[c];
}

// ---------------------------------------------------------------------------
// GroupNorm stats, two-stage.
// ---------------------------------------------------------------------------
__global__ __launch_bounds__(256) void gnstatsA(const float* __restrict__ in,
                                                float* __restrict__ stp, int cpg) {
  __shared__ float sh[256], sh2[256];
  const int g = blockIdx.x, b = blockIdx.y, t = threadIdx.x;
  const int n = cpg * HW;
  const int chunk = n >> 4;
  const float* __restrict__ base = in + (size_t)g * n + (size_t)b * chunk;
  float s = 0.f, ss = 0.f;
  for (int i = t; i < chunk; i += 256) {
    float v = base[i];
    s += v;
    ss += v * v;
  }
  sh[t] = s; sh2[t] = ss;
  __syncthreads();
  for (int w = 128; w > 0; w >>= 1) {
    if (t < w) { sh[t] += sh[t + w]; sh2[t] += sh2[t + w]; }
    __syncthreads();
  }
  if (t == 0) { stp[(g * 16 + b) * 2] = sh[0]; stp[(g * 16 + b) * 2 + 1] = sh2[0]; }
}

__global__ __launch_bounds__(64) void gnstatsB(const float* __restrict__ stp,
                                               float* __restrict__ st, int cpg) {
  const int g = blockIdx.x;
  if (threadIdx.x == 0) {
    float S = 0.f, SS = 0.f;
    for (int b = 0; b < 16; ++b) { S += stp[(g * 16 + b) * 2]; SS += stp[(g * 16 + b) * 2 + 1]; }
    float n = (float)(cpg * HW);
    float mean = S / n;
    float var = SS / n - mean * mean;
    st[g * 2] = mean;
    st[g * 2 + 1] = 1.0f / sqrtf(var + 1e-5f);
  }
}

// GroupNorm apply + ReLU, float32 out (reference output dtype).
__global__ __launch_bounds__(256) void gn_apply(
    const float* __restrict__ in, float* __restrict__ out, const float* __restrict__ st,
    const float* __restrict__ gs, const float* __restrict__ gb, int cpg) {
  const int idx = blockIdx.x * 256 + threadIdx.x;
  const int c = idx >> 12;
  const int g = c / cpg;
  float v = (in[idx] - st[g * 2]) * st[g * 2 + 1] * gs[c] + gb[c];
  out[idx] = fmaxf(v, 0.f);
}

// ---------------------------------------------------------------------------
extern "C" void kernel_launch(void* const* d_in, const int* in_sizes, int n_in,
                              void* d_out, int out_size, void* d_ws, size_t ws_size,
                              hipStream_t stream) {
  const float* x     = (const float*)d_in[0];
  const float* delta = (const float*)d_in[1];
  const float* Wq    = (const float*)d_in[2];
  const float* bq    = (const float*)d_in[3];
  const float* Ws    = (const float*)d_in[4];
  const float* bs    = (const float*)d_in[5];
  const float* scale = (const float*)d_in[6];
  const float* c1w = (const float*)d_in[7],  *c1b = (const float*)d_in[8];
  const float* g1s = (const float*)d_in[9],  *g1b = (const float*)d_in[10];
  const float* c2w = (const float*)d_in[11], *c2b = (const float*)d_in[12];
  const float* g2s = (const float*)d_in[13], *g2b = (const float*)d_in[14];
  const float* c3w = (const float*)d_in[15], *c3b = (const float*)d_in[16];
  const float* g3s = (const float*)d_in[17], *g3b = (const float*)d_in[18];

  float* ws   = (float*)d_ws;
  float* q_n  = ws;                       // 1,048,576
  float* s_n  = q_n + 1048576;            // 5,242,880
  float* c_s  = s_n + 5242880;            //   655,360
  float* mask = c_s + 655360;             //     2,560
  float* xo   = mask + 2560;              //    32,768
  float* st   = xo + 32768;               //        32
  float* stp  = st + 32;                  //       512 (128 used)
  float* wt   = stp + 512;                //   131,072
  float* un   = wt + 131072;              // union: part then conv temps
  float* part = un;                       // 1,310,720 (20*8*4096*2)
  float* t1   = un;                       //    65,536
  float* a1   = un + 65536;               //    65,536
  float* t2   = un + 131072;              //   262,144
  float* a2   = un + 393216;              //   262,144
  float* t3   = un + 655360;              //   524,288
  // total: 8,424,480 floats ~= 33.7 MB (proven fit)

  wtr_kernel<<<dim3(256, 2), 256, 0, stream>>>(Wq, Ws, wt);
  proj_kernel<<<dim3(64, 4, 6), 256, 0, stream>>>(x, wt, bq, bs, scale, q_n, s_n);
  agg_kernel<<<dim3(256, 5), 256, 0, stream>>>(delta, s_n, c_s, mask);
  attn_kernel<<<dim3(64, 8, 20), 256, 0, stream>>>(q_n, c_s, mask, part);
  merge_kernel<<<128, 256, 0, stream>>>(part, xo);

  conv_tile<8, 8, 5, 2, 4><<<dim3(16, 4), 256, 0, stream>>>(xo, c1w, c1b, t1);
  gnstatsA<<<dim3(4, 16), 256, 0, stream>>>(t1, stp, 4);
  gnstatsB<<<4, 64, 0, stream>>>(stp, st, 4);
  gn_apply<<<256, 256, 0, stream>>>(t1, a1, st, g1s, g1b, 4);

  conv_tile<16, 16, 3, 1, 8><<<dim3(16, 8), 256, 0, stream>>>(a1, c2w, c2b, t2);
  gnstatsA<<<dim3(4, 16), 256, 0, stream>>>(t2, stp + 128, 16);
  gnstatsB<<<4, 64, 0, stream>>>(stp + 128, st + 8, 16);
  gn_apply<<<1024, 256, 0, stream>>>(t2, a2, st + 8, g2s, g2b, 16);

  conv_tile<64, 16, 3, 1, 8><<<dim3(16, 16), 256, 0, stream>>>(a2, c3w, c3b, t3);
  gnstatsA<<<dim3(4, 16), 256, 0, stream>>>(t3, stp + 256, 32);
  gnstatsB<<<4, 64, 0, stream>>>(stp + 256, st + 16, 32);
  gn_apply<<<2048, 256, 0, stream>>>(t3, (float*)d_out, st + 16, g3s, g3b, 32);
}

// Round 18
// 204.949 us; speedup vs baseline: 2.4642x; 1.3186x over previous
//
#include <hip/hip_runtime.h>
#include <hip/hip_bf16.h>
#include <cstddef>

#define HW 4096   // 64*64

typedef __attribute__((ext_vector_type(8))) short bf16x8;
typedef __attribute__((ext_vector_type(4))) float f32x4;

__device__ __forceinline__ unsigned short f2b(float v) {
  __hip_bfloat16 b = __float2bfloat16(v);           // round-to-nearest
  return *reinterpret_cast<unsigned short*>(&b);
}

// ---------------------------------------------------------------------------
// W transpose: Wt[ci][co] = W[co][ci]
// ---------------------------------------------------------------------------
__global__ __launch_bounds__(256) void wtr_kernel(const float* __restrict__ Wq,
                                                  const float* __restrict__ Ws,
                                                  float* __restrict__ wt) {
  const int ci = blockIdx.x;
  const int w  = blockIdx.y;
  const int co = threadIdx.x;
  const float* __restrict__ W = (w == 0) ? Wq : Ws;
  wt[(size_t)w * 65536 + ci * 256 + co] = W[co * 256 + ci];
}

// ---------------------------------------------------------------------------
// Register-tile projection + fused per-head l2norm (verified).
// n==0 writes bf16 q (qb); n>=1 writes f32 s_n.
// ---------------------------------------------------------------------------
__global__ __launch_bounds__(256) void proj_kernel(
    const float* __restrict__ x, const float* __restrict__ wt,
    const float* __restrict__ bq, const float* __restrict__ bs,
    const float* __restrict__ scale,
    unsigned short* __restrict__ qb, float* __restrict__ s_n) {
  const int n   = blockIdx.z;
  const int p0  = blockIdx.x * 64;
  const int co0 = blockIdx.y * 64;
  const int t   = threadIdx.x;
  const int i   = t & 15;
  const int j   = t >> 4;
  const float* __restrict__ Wt = wt + (size_t)(n == 0 ? 0 : 1) * 65536;
  const float* __restrict__ B  = (n == 0) ? bq : bs;

  __shared__ float Xl[16][64];
  __shared__ float Wl[16][64];
  __shared__ float Sl[64][68];
  __shared__ float ssl[64][2];

  float acc[4][4];
#pragma unroll
  for (int a = 0; a < 4; ++a)
#pragma unroll
    for (int b = 0; b < 4; ++b) acc[a][b] = 0.f;

  for (int cc = 0; cc < 256; cc += 16) {
    __syncthreads();
#pragma unroll
    for (int pass = 0; pass < 4; ++pass) {
      int ci = pass * 4 + (t >> 6), lane = t & 63;
      Xl[ci][lane] = x[((size_t)n * 256 + cc + ci) * HW + p0 + lane];
      Wl[ci][lane] = Wt[(size_t)(cc + ci) * 256 + co0 + lane];
    }
    __syncthreads();
#pragma unroll
    for (int ci = 0; ci < 16; ++ci) {
      float4 X4 = *(const float4*)&Xl[ci][i * 4];
      float4 W4 = *(const float4*)&Wl[ci][j * 4];
      float xv[4] = {X4.x, X4.y, X4.z, X4.w};
      float wv[4] = {W4.x, W4.y, W4.z, W4.w};
#pragma unroll
      for (int a = 0; a < 4; ++a)
#pragma unroll
        for (int b = 0; b < 4; ++b) acc[a][b] += xv[a] * wv[b];
    }
  }

  __syncthreads();
#pragma unroll
  for (int a = 0; a < 4; ++a) {
    float4 v = make_float4(acc[a][0] + B[co0 + j * 4 + 0], acc[a][1] + B[co0 + j * 4 + 1],
                           acc[a][2] + B[co0 + j * 4 + 2], acc[a][3] + B[co0 + j * 4 + 3]);
    *(float4*)&Sl[i * 4 + a][j * 4] = v;
  }
  __syncthreads();

  if (t < 128) {
    int px = t & 63, hd = t >> 6;
    float ss = 0.f;
#pragma unroll
    for (int dd = 0; dd < 32; ++dd) {
      float v = Sl[px][hd * 32 + dd];
      ss += v * v;
    }
    ssl[px][hd] = fmaxf(sqrtf(ss), 1e-12f);
  }
  __syncthreads();

  const float qsc = scale[0] * 0.17677669529663687f;
  const int cin = t & 63, pg = t >> 6;
  if (n == 0) {
#pragma unroll
    for (int ii = 0; ii < 16; ++ii) {
      int px = pg * 16 + ii;
      float v = Sl[px][cin] / ssl[px][cin >> 5] * qsc;
      qb[(size_t)(p0 + px) * 256 + co0 + cin] = f2b(v);
    }
  } else {
    float* __restrict__ outp = s_n + (size_t)(n - 1) * HW * 256;
#pragma unroll
    for (int ii = 0; ii < 16; ++ii) {
      int px = pg * 16 + ii;
      float v = Sl[px][cin] / ssl[px][cin >> 5];
      outp[(size_t)(p0 + px) * 256 + co0 + cin] = v;
    }
  }
}

// ---------------------------------------------------------------------------
// Patch aggregation -> cb (bf16) [8][2560][32], mask[2560].
// ---------------------------------------------------------------------------
__global__ __launch_bounds__(256) void agg_kernel(
    const float* __restrict__ delta, const float* __restrict__ s_n,
    unsigned short* __restrict__ cb, float* __restrict__ mask) {
  const int s = blockIdx.x;
  const int k = blockIdx.y;
  const int t = threadIdx.x;
  __shared__ float fgl[16];
  const int sy = (s >> 4) * 4, sx = (s & 15) * 4;
  if (t < 16) {
    int y0 = (sy + (t >> 2)) * 8, x0 = (sx + (t & 3)) * 8;
    fgl[t] = delta[(size_t)k * 512 * 512 + (size_t)y0 * 512 + x0];
  }
  __syncthreads();
  const int h = t >> 5, d = t & 31;
  float af = 0.f, ab = 0.f;
#pragma unroll
  for (int l = 0; l < 16; ++l) {
    int pix = (sy + (l >> 2)) * 64 + sx + (l & 3);
    float sv = s_n[((size_t)k * HW + pix) * 256 + h * 32 + d];
    float f = fgl[l];
    af += f * sv;
    ab += (1.f - f) * sv;
  }
  float ssf = af * af, ssb = ab * ab;
#pragma unroll
  for (int m = 1; m <= 16; m <<= 1) {
    ssf += __shfl_xor(ssf, m);
    ssb += __shfl_xor(ssb, m);
  }
  float vf = af / fmaxf(sqrtf(ssf), 1e-12f);
  float vb = ab / fmaxf(sqrtf(ssb), 1e-12f);
  const int jf = k * 512 + s, jb = jf + 256;
  cb[((size_t)h * 2560 + jf) * 32 + d] = f2b(vf);
  cb[((size_t)h * 2560 + jb) * 32 + d] = f2b(vb);
  if (t == 0) {
    float fs = 0.f;
#pragma unroll
    for (int l = 0; l < 16; ++l) fs += fgl[l];
    mask[jf] = (fs < 1.f) ? -1e30f : 0.f;
    mask[jb] = ((16.f - fs) < 1.f) ? -1e30f : 0.f;
  }
}

// ---------------------------------------------------------------------------
// Attention via bf16 MFMA 16x16x32 (K = head_dim = 32, one MFMA per tile).
// grid (64 px-tiles of 64, 8 heads), block 256 = 4 waves; wave = 16 px rows.
// A: lane holds q[p0 + (l&15)][k-chunk (l>>4)*8]; B: cb[key=(l&15)][same chunk]
// D: col=lane&15 (key), row=(lane>>4)*4+r (px). No LDS operands, no partials.
// ---------------------------------------------------------------------------
__global__ __launch_bounds__(256) void attn_kernel(
    const unsigned short* __restrict__ qb, const unsigned short* __restrict__ cb,
    const float* __restrict__ mask, float* __restrict__ xo) {
  const int t = threadIdx.x;
  const int wv = t >> 6;
  const int l = t & 63;
  const int h = blockIdx.y;
  const int p0 = blockIdx.x * 64 + wv * 16;

  __shared__ float ml[2560];
  for (int i = t; i < 2560; i += 256) ml[i] = mask[i];

  const bf16x8 a = *(const bf16x8*)&qb[(size_t)(p0 + (l & 15)) * 256 + h * 32 + (l >> 4) * 8];
  __syncthreads();

  float num[4] = {0.f, 0.f, 0.f, 0.f}, den[4] = {0.f, 0.f, 0.f, 0.f};
  const size_t cbase = (size_t)h * 2560 * 32 + ((size_t)(l >> 4)) * 8;

  for (int j0 = 0; j0 < 2560; j0 += 16) {
    bf16x8 b = *(const bf16x8*)&cb[cbase + (size_t)(j0 + (l & 15)) * 32];
    f32x4 dacc = {0.f, 0.f, 0.f, 0.f};
    dacc = __builtin_amdgcn_mfma_f32_16x16x32_bf16(a, b, dacc, 0, 0, 0);
    float m = ml[j0 + (l & 15)];
    float cv = ((j0 & 511) < 256) ? 1.f : 0.f;   // uniform per 16-key tile
#pragma unroll
    for (int r = 0; r < 4; ++r) {
      float e = __expf(dacc[r] + m);             // masked -> exp(-1e30)=0
      den[r] += e;
      num[r] += cv * e;
    }
  }

  // sum over key-lanes (bits 0..3 of lane)
#pragma unroll
  for (int r = 0; r < 4; ++r) {
#pragma unroll
    for (int msk = 1; msk <= 8; msk <<= 1) {
      den[r] += __shfl_xor(den[r], msk);
      num[r] += __shfl_xor(num[r], msk);
    }
  }
  if ((l & 15) == 0) {
#pragma unroll
    for (int r = 0; r < 4; ++r) {
      int px = p0 + (l >> 4) * 4 + r;
      xo[(size_t)h * HW + px] = num[r] / den[r];
    }
  }
}

// ---------------------------------------------------------------------------
// LDS-staged register-tiled conv (verified, round 17).
// ---------------------------------------------------------------------------
template <int CI, int CIC, int KS, int PAD, int COT>
__global__ __launch_bounds__(256) void conv_tile(
    const float* __restrict__ in, const float* __restrict__ w,
    const float* __restrict__ b, float* __restrict__ out) {
  constexpr int R = 4 + KS - 1;
  constexpr int C = 64 + 2 * PAD;
  const int t   = threadIdx.x;
  const int y0  = blockIdx.x * 4;
  const int co0 = blockIdx.y * COT;

  __shared__ float Xl[CIC][R][C];
  __shared__ float Wl[CIC][KS * KS][COT];

  const int xi = t & 63;
  const int yr = t >> 6;

  float acc[COT];
#pragma unroll
  for (int c = 0; c < COT; ++c) acc[c] = b[co0 + c];

  for (int cb2 = 0; cb2 < CI; cb2 += CIC) {
    __syncthreads();
    for (int idx = t; idx < CIC * R * C; idx += 256) {
      int ci = idx / (R * C), rem = idx % (R * C), pr = rem / C, pc = rem % C;
      int iy = y0 + pr - PAD, ix = pc - PAD;
      float v = 0.f;
      if (iy >= 0 && iy < 64 && ix >= 0 && ix < 64)
        v = in[(size_t)(cb2 + ci) * HW + iy * 64 + ix];
      Xl[ci][pr][pc] = v;
    }
    for (int idx = t; idx < CIC * KS * KS * COT; idx += 256) {
      int ci = idx / (KS * KS * COT), rem = idx % (KS * KS * COT);
      int kk = rem / COT, c = rem % COT;
      Wl[ci][kk][c] = w[(size_t)((co0 + c) * CI + cb2 + ci) * KS * KS + kk];
    }
    __syncthreads();
#pragma unroll
    for (int ci = 0; ci < CIC; ++ci)
#pragma unroll
      for (int ky = 0; ky < KS; ++ky)
#pragma unroll
        for (int kx = 0; kx < KS; ++kx) {
          float xv = Xl[ci][yr + ky][xi + kx];
          const float4* w4 = (const float4*)&Wl[ci][ky * KS + kx][0];
#pragma unroll
          for (int c4 = 0; c4 < COT / 4; ++c4) {
            float4 wv = w4[c4];
            acc[c4 * 4 + 0] += xv * wv.x;
            acc[c4 * 4 + 1] += xv * wv.y;
            acc[c4 * 4 + 2] += xv * wv.z;
            acc[c4 * 4 + 3] += xv * wv.w;
          }
        }
  }
  const int p = (y0 + yr) * 64 + xi;
#pragma unroll
  for (int c = 0; c < COT; ++c)
    out[(size_t)(co0 + c) * HW + p] = acc[c];
}

// ---------------------------------------------------------------------------
// GroupNorm stats, two-stage.
// ---------------------------------------------------------------------------
__global__ __launch_bounds__(256) void gnstatsA(const float* __restrict__ in,
                                                float* __restrict__ stp, int cpg) {
  __shared__ float sh[256], sh2[256];
  const int g = blockIdx.x, b = blockIdx.y, t = threadIdx.x;
  const int n = cpg * HW;
  const int chunk = n >> 4;
  const float* __restrict__ base = in + (size_t)g * n + (size_t)b * chunk;
  float s = 0.f, ss = 0.f;
  for (int i = t; i < chunk; i += 256) {
    float v = base[i];
    s += v;
    ss += v * v;
  }
  sh[t] = s; sh2[t] = ss;
  __syncthreads();
  for (int w = 128; w > 0; w >>= 1) {
    if (t < w) { sh[t] += sh[t + w]; sh2[t] += sh2[t + w]; }
    __syncthreads();
  }
  if (t == 0) { stp[(g * 16 + b) * 2] = sh[0]; stp[(g * 16 + b) * 2 + 1] = sh2[0]; }
}

__global__ __launch_bounds__(64) void gnstatsB(const float* __restrict__ stp,
                                               float* __restrict__ st, int cpg) {
  const int g = blockIdx.x;
  if (threadIdx.x == 0) {
    float S = 0.f, SS = 0.f;
    for (int b = 0; b < 16; ++b) { S += stp[(g * 16 + b) * 2]; SS += stp[(g * 16 + b) * 2 + 1]; }
    float n = (float)(cpg * HW);
    float mean = S / n;
    float var = SS / n - mean * mean;
    st[g * 2] = mean;
    st[g * 2 + 1] = 1.0f / sqrtf(var + 1e-5f);
  }
}

// GroupNorm apply + ReLU, float32 out (reference output dtype).
__global__ __launch_bounds__(256) void gn_apply(
    const float* __restrict__ in, float* __restrict__ out, const float* __restrict__ st,
    const float* __restrict__ gs, const float* __restrict__ gb, int cpg) {
  const int idx = blockIdx.x * 256 + threadIdx.x;
  const int c = idx >> 12;
  const int g = c / cpg;
  float v = (in[idx] - st[g * 2]) * st[g * 2 + 1] * gs[c] + gb[c];
  out[idx] = fmaxf(v, 0.f);
}

// ---------------------------------------------------------------------------
extern "C" void kernel_launch(void* const* d_in, const int* in_sizes, int n_in,
                              void* d_out, int out_size, void* d_ws, size_t ws_size,
                              hipStream_t stream) {
  const float* x     = (const float*)d_in[0];
  const float* delta = (const float*)d_in[1];
  const float* Wq    = (const float*)d_in[2];
  const float* bq    = (const float*)d_in[3];
  const float* Ws    = (const float*)d_in[4];
  const float* bs    = (const float*)d_in[5];
  const float* scale = (const float*)d_in[6];
  const float* c1w = (const float*)d_in[7],  *c1b = (const float*)d_in[8];
  const float* g1s = (const float*)d_in[9],  *g1b = (const float*)d_in[10];
  const float* c2w = (const float*)d_in[11], *c2b = (const float*)d_in[12];
  const float* g2s = (const float*)d_in[13], *g2b = (const float*)d_in[14];
  const float* c3w = (const float*)d_in[15], *c3b = (const float*)d_in[16];
  const float* g3s = (const float*)d_in[17], *g3b = (const float*)d_in[18];

  float* ws   = (float*)d_ws;
  float* s_n  = ws;                       // 5,242,880
  unsigned short* qb = (unsigned short*)(s_n + 5242880);   // 1,048,576 u16 (524,288 f)
  unsigned short* cb = qb + 1048576;      //   655,360 u16 (327,680 f)
  float* mask = (float*)(cb + 655360);    //     2,560
  float* xo   = mask + 2560;              //    32,768
  float* st   = xo + 32768;               //        32
  float* stp  = st + 32;                  //       512 (96 used)
  float* wt   = stp + 512;                //   131,072
  float* un   = wt + 131072;              // conv temps union
  float* t1   = un;                       //    65,536
  float* a1   = un + 65536;               //    65,536
  float* t2   = un + 131072;              //   262,144
  float* a2   = un + 393216;              //   262,144
  float* t3   = un + 655360;              //   524,288
  // total: 7,441,440 floats ~= 29.8 MB

  wtr_kernel<<<dim3(256, 2), 256, 0, stream>>>(Wq, Ws, wt);
  proj_kernel<<<dim3(64, 4, 6), 256, 0, stream>>>(x, wt, bq, bs, scale, qb, s_n);
  agg_kernel<<<dim3(256, 5), 256, 0, stream>>>(delta, s_n, cb, mask);
  attn_kernel<<<dim3(64, 8), 256, 0, stream>>>(qb, cb, mask, xo);

  conv_tile<8, 8, 5, 2, 4><<<dim3(16, 4), 256, 0, stream>>>(xo, c1w, c1b, t1);
  gnstatsA<<<dim3(4, 16), 256, 0, stream>>>(t1, stp, 4);
  gnstatsB<<<4, 64, 0, stream>>>(stp, st, 4);
  gn_apply<<<256, 256, 0, stream>>>(t1, a1, st, g1s, g1b, 4);

  conv_tile<16, 16, 3, 1, 8><<<dim3(16, 8), 256, 0, stream>>>(a1, c2w, c2b, t2);
  gnstatsA<<<dim3(4, 16), 256, 0, stream>>>(t2, stp + 128, 16);
  gnstatsB<<<4, 64, 0, stream>>>(stp + 128, st + 8, 16);
  gn_apply<<<1024, 256, 0, stream>>>(t2, a2, st + 8, g2s, g2b, 16);

  conv_tile<64, 16, 3, 1, 8><<<dim3(16, 16), 256, 0, stream>>>(a2, c3w, c3b, t3);
  gnstatsA<<<dim3(4, 16), 256, 0, stream>>>(t3, stp + 256, 32);
  gnstatsB<<<4, 64, 0, stream>>>(stp + 256, st + 16, 32);
  gn_apply<<<2048, 256, 0, stream>>>(t3, (float*)d_out, st + 16, g3s, g3b, 32);
}

// Round 19
// 164.794 us; speedup vs baseline: 3.0647x; 1.2437x over previous
//
#include <hip/hip_runtime.h>
#include <hip/hip_bf16.h>
#include <cstddef>

#define HW 4096   // 64*64

typedef __attribute__((ext_vector_type(8))) short bf16x8;
typedef __attribute__((ext_vector_type(4))) float f32x4;

__device__ __forceinline__ unsigned short f2b(float v) {
  __hip_bfloat16 b = __float2bfloat16(v);           // round-to-nearest
  return *reinterpret_cast<unsigned short*>(&b);
}

// ---------------------------------------------------------------------------
// W transpose: Wt[ci][co] = W[co][ci]
// ---------------------------------------------------------------------------
__global__ __launch_bounds__(256) void wtr_kernel(const float* __restrict__ Wq,
                                                  const float* __restrict__ Ws,
                                                  float* __restrict__ wt) {
  const int ci = blockIdx.x;
  const int w  = blockIdx.y;
  const int co = threadIdx.x;
  const float* __restrict__ W = (w == 0) ? Wq : Ws;
  wt[(size_t)w * 65536 + ci * 256 + co] = W[co * 256 + ci];
}

// ---------------------------------------------------------------------------
// Register-tile projection + fused per-head l2norm (verified).
// n==0 writes bf16 q (qb); n>=1 writes f32 s_n.
// ---------------------------------------------------------------------------
__global__ __launch_bounds__(256) void proj_kernel(
    const float* __restrict__ x, const float* __restrict__ wt,
    const float* __restrict__ bq, const float* __restrict__ bs,
    const float* __restrict__ scale,
    unsigned short* __restrict__ qb, float* __restrict__ s_n) {
  const int n   = blockIdx.z;
  const int p0  = blockIdx.x * 64;
  const int co0 = blockIdx.y * 64;
  const int t   = threadIdx.x;
  const int i   = t & 15;
  const int j   = t >> 4;
  const float* __restrict__ Wt = wt + (size_t)(n == 0 ? 0 : 1) * 65536;
  const float* __restrict__ B  = (n == 0) ? bq : bs;

  __shared__ float Xl[16][64];
  __shared__ float Wl[16][64];
  __shared__ float Sl[64][68];
  __shared__ float ssl[64][2];

  float acc[4][4];
#pragma unroll
  for (int a = 0; a < 4; ++a)
#pragma unroll
    for (int b = 0; b < 4; ++b) acc[a][b] = 0.f;

  for (int cc = 0; cc < 256; cc += 16) {
    __syncthreads();
#pragma unroll
    for (int pass = 0; pass < 4; ++pass) {
      int ci = pass * 4 + (t >> 6), lane = t & 63;
      Xl[ci][lane] = x[((size_t)n * 256 + cc + ci) * HW + p0 + lane];
      Wl[ci][lane] = Wt[(size_t)(cc + ci) * 256 + co0 + lane];
    }
    __syncthreads();
#pragma unroll
    for (int ci = 0; ci < 16; ++ci) {
      float4 X4 = *(const float4*)&Xl[ci][i * 4];
      float4 W4 = *(const float4*)&Wl[ci][j * 4];
      float xv[4] = {X4.x, X4.y, X4.z, X4.w};
      float wv[4] = {W4.x, W4.y, W4.z, W4.w};
#pragma unroll
      for (int a = 0; a < 4; ++a)
#pragma unroll
        for (int b = 0; b < 4; ++b) acc[a][b] += xv[a] * wv[b];
    }
  }

  __syncthreads();
#pragma unroll
  for (int a = 0; a < 4; ++a) {
    float4 v = make_float4(acc[a][0] + B[co0 + j * 4 + 0], acc[a][1] + B[co0 + j * 4 + 1],
                           acc[a][2] + B[co0 + j * 4 + 2], acc[a][3] + B[co0 + j * 4 + 3]);
    *(float4*)&Sl[i * 4 + a][j * 4] = v;
  }
  __syncthreads();

  if (t < 128) {
    int px = t & 63, hd = t >> 6;
    float ss = 0.f;
#pragma unroll
    for (int dd = 0; dd < 32; ++dd) {
      float v = Sl[px][hd * 32 + dd];
      ss += v * v;
    }
    ssl[px][hd] = fmaxf(sqrtf(ss), 1e-12f);
  }
  __syncthreads();

  const float qsc = scale[0] * 0.17677669529663687f;
  const int cin = t & 63, pg = t >> 6;
  if (n == 0) {
#pragma unroll
    for (int ii = 0; ii < 16; ++ii) {
      int px = pg * 16 + ii;
      float v = Sl[px][cin] / ssl[px][cin >> 5] * qsc;
      qb[(size_t)(p0 + px) * 256 + co0 + cin] = f2b(v);
    }
  } else {
    float* __restrict__ outp = s_n + (size_t)(n - 1) * HW * 256;
#pragma unroll
    for (int ii = 0; ii < 16; ++ii) {
      int px = pg * 16 + ii;
      float v = Sl[px][cin] / ssl[px][cin >> 5];
      outp[(size_t)(p0 + px) * 256 + co0 + cin] = v;
    }
  }
}

// ---------------------------------------------------------------------------
// Patch aggregation -> cb (bf16) [8][2560][32], mask[2560].
// ---------------------------------------------------------------------------
__global__ __launch_bounds__(256) void agg_kernel(
    const float* __restrict__ delta, const float* __restrict__ s_n,
    unsigned short* __restrict__ cb, float* __restrict__ mask) {
  const int s = blockIdx.x;
  const int k = blockIdx.y;
  const int t = threadIdx.x;
  __shared__ float fgl[16];
  const int sy = (s >> 4) * 4, sx = (s & 15) * 4;
  if (t < 16) {
    int y0 = (sy + (t >> 2)) * 8, x0 = (sx + (t & 3)) * 8;
    fgl[t] = delta[(size_t)k * 512 * 512 + (size_t)y0 * 512 + x0];
  }
  __syncthreads();
  const int h = t >> 5, d = t & 31;
  float af = 0.f, ab = 0.f;
#pragma unroll
  for (int l = 0; l < 16; ++l) {
    int pix = (sy + (l >> 2)) * 64 + sx + (l & 3);
    float sv = s_n[((size_t)k * HW + pix) * 256 + h * 32 + d];
    float f = fgl[l];
    af += f * sv;
    ab += (1.f - f) * sv;
  }
  float ssf = af * af, ssb = ab * ab;
#pragma unroll
  for (int m = 1; m <= 16; m <<= 1) {
    ssf += __shfl_xor(ssf, m);
    ssb += __shfl_xor(ssb, m);
  }
  float vf = af / fmaxf(sqrtf(ssf), 1e-12f);
  float vb = ab / fmaxf(sqrtf(ssb), 1e-12f);
  const int jf = k * 512 + s, jb = jf + 256;
  cb[((size_t)h * 2560 + jf) * 32 + d] = f2b(vf);
  cb[((size_t)h * 2560 + jb) * 32 + d] = f2b(vb);
  if (t == 0) {
    float fs = 0.f;
#pragma unroll
    for (int l = 0; l < 16; ++l) fs += fgl[l];
    mask[jf] = (fs < 1.f) ? -1e30f : 0.f;
    mask[jb] = ((16.f - fs) < 1.f) ? -1e30f : 0.f;
  }
}

// ---------------------------------------------------------------------------
// Attention via bf16 MFMA 16x16x32 (verified, round 18).
// ---------------------------------------------------------------------------
__global__ __launch_bounds__(256) void attn_kernel(
    const unsigned short* __restrict__ qb, const unsigned short* __restrict__ cb,
    const float* __restrict__ mask, float* __restrict__ xo) {
  const int t = threadIdx.x;
  const int wv = t >> 6;
  const int l = t & 63;
  const int h = blockIdx.y;
  const int p0 = blockIdx.x * 64 + wv * 16;

  __shared__ float ml[2560];
  for (int i = t; i < 2560; i += 256) ml[i] = mask[i];

  const bf16x8 a = *(const bf16x8*)&qb[(size_t)(p0 + (l & 15)) * 256 + h * 32 + (l >> 4) * 8];
  __syncthreads();

  float num[4] = {0.f, 0.f, 0.f, 0.f}, den[4] = {0.f, 0.f, 0.f, 0.f};
  const size_t cbase = (size_t)h * 2560 * 32 + ((size_t)(l >> 4)) * 8;

  for (int j0 = 0; j0 < 2560; j0 += 16) {
    bf16x8 b = *(const bf16x8*)&cb[cbase + (size_t)(j0 + (l & 15)) * 32];
    f32x4 dacc = {0.f, 0.f, 0.f, 0.f};
    dacc = __builtin_amdgcn_mfma_f32_16x16x32_bf16(a, b, dacc, 0, 0, 0);
    float m = ml[j0 + (l & 15)];
    float cv = ((j0 & 511) < 256) ? 1.f : 0.f;
#pragma unroll
    for (int r = 0; r < 4; ++r) {
      float e = __expf(dacc[r] + m);
      den[r] += e;
      num[r] += cv * e;
    }
  }

#pragma unroll
  for (int r = 0; r < 4; ++r) {
#pragma unroll
    for (int msk = 1; msk <= 8; msk <<= 1) {
      den[r] += __shfl_xor(den[r], msk);
      num[r] += __shfl_xor(num[r], msk);
    }
  }
  if ((l & 15) == 0) {
#pragma unroll
    for (int r = 0; r < 4; ++r) {
      int px = p0 + (l >> 4) * 4 + r;
      xo[(size_t)h * HW + px] = num[r] / den[r];
    }
  }
}

// ---------------------------------------------------------------------------
// Conv, ci-split partials: blockIdx.z = ci-split; pp[z][co][p] (no bias).
// COT==2 uses scalar W reads; COT%4==0 uses float4 broadcast.
// ---------------------------------------------------------------------------
template <int CIC, int KS, int PAD, int COT>
__global__ __launch_bounds__(256) void conv_split(
    const float* __restrict__ in, const float* __restrict__ w,
    float* __restrict__ pp, int CI) {
  constexpr int R = 4 + KS - 1;
  constexpr int C = 64 + 2 * PAD;
  const int t   = threadIdx.x;
  const int y0  = blockIdx.x * 4;
  const int co0 = blockIdx.y * COT;
  const int cb0 = blockIdx.z * CIC;
  const int CO  = gridDim.y * COT;

  __shared__ float Xl[CIC][R][C];
  __shared__ float Wl[CIC][KS * KS][COT];

  const int xi = t & 63;
  const int yr = t >> 6;

  float acc[COT];
#pragma unroll
  for (int c = 0; c < COT; ++c) acc[c] = 0.f;

  // stage X patch (zero-padded)
  for (int idx = t; idx < CIC * R * C; idx += 256) {
    int ci = idx / (R * C), rem = idx % (R * C), pr = rem / C, pc = rem % C;
    int iy = y0 + pr - PAD, ix = pc - PAD;
    float v = 0.f;
    if (iy >= 0 && iy < 64 && ix >= 0 && ix < 64)
      v = in[(size_t)(cb0 + ci) * HW + iy * 64 + ix];
    Xl[ci][pr][pc] = v;
  }
  // stage W
  for (int idx = t; idx < CIC * KS * KS * COT; idx += 256) {
    int ci = idx / (KS * KS * COT), rem = idx % (KS * KS * COT);
    int kk = rem / COT, c = rem % COT;
    Wl[ci][kk][c] = w[(size_t)((co0 + c) * CI + cb0 + ci) * KS * KS + kk];
  }
  __syncthreads();

#pragma unroll
  for (int ci = 0; ci < CIC; ++ci)
#pragma unroll
    for (int ky = 0; ky < KS; ++ky)
#pragma unroll
      for (int kx = 0; kx < KS; ++kx) {
        float xv = Xl[ci][yr + ky][xi + kx];
        if constexpr (COT % 4 == 0) {
          const float4* w4 = (const float4*)&Wl[ci][ky * KS + kx][0];
#pragma unroll
          for (int c4 = 0; c4 < COT / 4; ++c4) {
            float4 wv = w4[c4];
            acc[c4 * 4 + 0] += xv * wv.x;
            acc[c4 * 4 + 1] += xv * wv.y;
            acc[c4 * 4 + 2] += xv * wv.z;
            acc[c4 * 4 + 3] += xv * wv.w;
          }
        } else {
#pragma unroll
          for (int c = 0; c < COT; ++c) acc[c] += xv * Wl[ci][ky * KS + kx][c];
        }
      }

  const int p = (y0 + yr) * 64 + xi;
  float* o = pp + (size_t)blockIdx.z * CO * HW;
#pragma unroll
  for (int c = 0; c < COT; ++c)
    o[(size_t)(co0 + c) * HW + p] = acc[c];
}

// merge S ci-split partials + bias
__global__ __launch_bounds__(256) void conv_merge(
    const float* __restrict__ pp, const float* __restrict__ b,
    float* __restrict__ out, int S, int CO) {
  const int idx = blockIdx.x * 256 + threadIdx.x;
  const int c = idx >> 12;
  float v = b[c];
  const size_t stride = (size_t)CO * HW;
  for (int s = 0; s < S; ++s) v += pp[(size_t)s * stride + idx];
  out[idx] = v;
}

// ---------------------------------------------------------------------------
// GroupNorm stats, two-stage.
// ---------------------------------------------------------------------------
__global__ __launch_bounds__(256) void gnstatsA(const float* __restrict__ in,
                                                float* __restrict__ stp, int cpg) {
  __shared__ float sh[256], sh2[256];
  const int g = blockIdx.x, b = blockIdx.y, t = threadIdx.x;
  const int n = cpg * HW;
  const int chunk = n >> 4;
  const float* __restrict__ base = in + (size_t)g * n + (size_t)b * chunk;
  float s = 0.f, ss = 0.f;
  for (int i = t; i < chunk; i += 256) {
    float v = base[i];
    s += v;
    ss += v * v;
  }
  sh[t] = s; sh2[t] = ss;
  __syncthreads();
  for (int w = 128; w > 0; w >>= 1) {
    if (t < w) { sh[t] += sh[t + w]; sh2[t] += sh2[t + w]; }
    __syncthreads();
  }
  if (t == 0) { stp[(g * 16 + b) * 2] = sh[0]; stp[(g * 16 + b) * 2 + 1] = sh2[0]; }
}

__global__ __launch_bounds__(64) void gnstatsB(const float* __restrict__ stp,
                                               float* __restrict__ st, int cpg) {
  const int g = blockIdx.x;
  if (threadIdx.x == 0) {
    float S = 0.f, SS = 0.f;
    for (int b = 0; b < 16; ++b) { S += stp[(g * 16 + b) * 2]; SS += stp[(g * 16 + b) * 2 + 1]; }
    float n = (float)(cpg * HW);
    float mean = S / n;
    float var = SS / n - mean * mean;
    st[g * 2] = mean;
    st[g * 2 + 1] = 1.0f / sqrtf(var + 1e-5f);
  }
}

// GroupNorm apply + ReLU, float32 out (reference output dtype).
__global__ __launch_bounds__(256) void gn_apply(
    const float* __restrict__ in, float* __restrict__ out, const float* __restrict__ st,
    const float* __restrict__ gs, const float* __restrict__ gb, int cpg) {
  const int idx = blockIdx.x * 256 + threadIdx.x;
  const int c = idx >> 12;
  const int g = c / cpg;
  float v = (in[idx] - st[g * 2]) * st[g * 2 + 1] * gs[c] + gb[c];
  out[idx] = fmaxf(v, 0.f);
}

// ---------------------------------------------------------------------------
extern "C" void kernel_launch(void* const* d_in, const int* in_sizes, int n_in,
                              void* d_out, int out_size, void* d_ws, size_t ws_size,
                              hipStream_t stream) {
  const float* x     = (const float*)d_in[0];
  const float* delta = (const float*)d_in[1];
  const float* Wq    = (const float*)d_in[2];
  const float* bq    = (const float*)d_in[3];
  const float* Ws    = (const float*)d_in[4];
  const float* bs    = (const float*)d_in[5];
  const float* scale = (const float*)d_in[6];
  const float* c1w = (const float*)d_in[7],  *c1b = (const float*)d_in[8];
  const float* g1s = (const float*)d_in[9],  *g1b = (const float*)d_in[10];
  const float* c2w = (const float*)d_in[11], *c2b = (const float*)d_in[12];
  const float* g2s = (const float*)d_in[13], *g2b = (const float*)d_in[14];
  const float* c3w = (const float*)d_in[15], *c3b = (const float*)d_in[16];
  const float* g3s = (const float*)d_in[17], *g3b = (const float*)d_in[18];

  float* ws   = (float*)d_ws;
  float* s_n  = ws;                       // 5,242,880 (dead after agg -> reused)
  unsigned short* qb = (unsigned short*)(s_n + 5242880);   // 1,048,576 u16
  unsigned short* cb = qb + 1048576;      //   655,360 u16
  float* mask = (float*)(cb + 655360);    //     2,560
  float* xo   = mask + 2560;              //    32,768
  float* st   = xo + 32768;               //        32
  float* stp  = st + 32;                  //       512 (96 used)
  float* wt   = stp + 512;                //   131,072
  // conv temporaries reuse the dead s_n region:
  float* pp   = s_n;                      // up to 2,097,152 (4 x 128 x 4096)
  float* t1   = s_n + 2097152;            //    65,536
  float* a1   = t1 + 65536;               //    65,536
  float* t2   = a1 + 65536;               //   262,144
  float* a2   = t2 + 262144;              //   262,144
  float* t3   = a2 + 262144;              //   524,288  (ends at 3,276,800 < 5,242,880)
  // total ws: 7,441,440 floats ~= 29.8 MB (unchanged from round 18)

  wtr_kernel<<<dim3(256, 2), 256, 0, stream>>>(Wq, Ws, wt);
  proj_kernel<<<dim3(64, 4, 6), 256, 0, stream>>>(x, wt, bq, bs, scale, qb, s_n);
  agg_kernel<<<dim3(256, 5), 256, 0, stream>>>(delta, s_n, cb, mask);
  attn_kernel<<<dim3(64, 8), 256, 0, stream>>>(qb, cb, mask, xo);

  // conv1: CI=8 -> 2 splits x CIC=4, COT=2, grid (16,8,2)
  conv_split<4, 5, 2, 2><<<dim3(16, 8, 2), 256, 0, stream>>>(xo, c1w, pp, 8);
  conv_merge<<<256, 256, 0, stream>>>(pp, c1b, t1, 2, 16);
  gnstatsA<<<dim3(4, 16), 256, 0, stream>>>(t1, stp, 4);
  gnstatsB<<<4, 64, 0, stream>>>(stp, st, 4);
  gn_apply<<<256, 256, 0, stream>>>(t1, a1, st, g1s, g1b, 4);

  // conv2: CI=16 -> 2 splits x CIC=8, COT=4, grid (16,16,2)
  conv_split<8, 3, 1, 4><<<dim3(16, 16, 2), 256, 0, stream>>>(a1, c2w, pp, 16);
  conv_merge<<<1024, 256, 0, stream>>>(pp, c2b, t2, 2, 64);
  gnstatsA<<<dim3(4, 16), 256, 0, stream>>>(t2, stp + 128, 16);
  gnstatsB<<<4, 64, 0, stream>>>(stp + 128, st + 8, 16);
  gn_apply<<<1024, 256, 0, stream>>>(t2, a2, st + 8, g2s, g2b, 16);

  // conv3: CI=64 -> 4 splits x CIC=16, COT=8, grid (16,16,4)
  conv_split<16, 3, 1, 8><<<dim3(16, 16, 4), 256, 0, stream>>>(a2, c3w, pp, 64);
  conv_merge<<<2048, 256, 0, stream>>>(pp, c3b, t3, 4, 128);
  gnstatsA<<<dim3(4, 16), 256, 0, stream>>>(t3, stp + 256, 32);
  gnstatsB<<<4, 64, 0, stream>>>(stp + 256, st + 16, 32);
  gn_apply<<<2048, 256, 0, stream>>>(t3, (float*)d_out, st + 16, g3s, g3b, 32);
}